// Round 2
// baseline (226.099 us; speedup 1.0000x reference)
//
#include <hip/hip_runtime.h>
#include <math.h>

#define BB 8
#define CC 128
#define N0 4096
#define MSGN 4
#define NTOT 4100
#define IMG 64
#define NPAD 4160            // 130 tiles of 32 q-rows (2 waves/block x 65 blocks)
#define LMP1 320
#define LMP2 1088

// ---------------- workspace layout (float indices) ----------------
#define OFF_WFQ    0
#define OFF_WFKV1  8192
#define OFF_WFKV2  16384
#define OFF_WFPROJ 24576
#define OFF_WFSR1  32768        // K=2048: 131072 f
#define OFF_WFSR2  163840       // K=512:  32768 f
#define OFF_QH     196608       // fp16 8*4*4160*32 = 2129920 f -> end 2326528
#define OFF_XK1    2326528      // 133120 f (dead after kv_gemm)
#define OFF_XK2    2459648      // 526336 f (dead after kv_gemm)
#define OFF_KV1O   2985984      // 266240 f (dead after pack_kv)
#define OFF_KV2O   3252224      // 1052672 f (dead after pack_kv)
#define OFF_KH1    4304896      // 81920 f
#define OFF_VT1    4386816      // 81920 f  ([b,h2][key>>2][d16:16][dhalf][key&3])
#define OFF_KH2    4468736      // 278528 f
#define OFF_VT2    4747264      // 278528 f -> end 5025792
#define OFF_XP     5025792      // normalized attn O frags (fp16): 2101248 f -> end 7127040 (28.5 MB)

typedef _Float16 half8v __attribute__((ext_vector_type(8)));
typedef _Float16 half4v __attribute__((ext_vector_type(4)));
typedef float f32x4 __attribute__((ext_vector_type(4)));

__device__ __forceinline__ size_t af_idx(int m, int k, int Kc) {
    return ((size_t)((m >> 4) * Kc + (k >> 5)) * 64 + ((k >> 3) & 3) * 16 + (m & 15)) * 8 + (k & 7);
}

// exp2 (scores carry log2e folded into Q scale)
__device__ __forceinline__ float exp2_fast(float x) {
#if __has_builtin(__builtin_amdgcn_exp2f)
    return __builtin_amdgcn_exp2f(x);
#else
    return __expf(x * 0.6931471805599453f);
#endif
}

// ---------------- weight prep (B-frag swizzle) + Q-pad zero ----------------
__global__ void prep_weights(const float* __restrict__ Wq, const float* __restrict__ kv1,
                             const float* __restrict__ kv2, const float* __restrict__ proj,
                             const float* __restrict__ sr1w, const float* __restrict__ sr2w,
                             float* __restrict__ ws, _Float16* __restrict__ Qh) {
    int u = blockIdx.x * blockDim.x + threadIdx.x;
    if (u >= 49152) {
        int idx = u - 49152;
        if (idx >= BB * 4 * (NPAD - NTOT) * 32) return;
        int d = idx & 31;
        int rest = idx >> 5;
        int n = NTOT + rest % (NPAD - NTOT);
        int rest2 = rest / (NPAD - NTOT);
        int hg = rest2 & 3;
        int b = rest2 >> 2;
        Qh[((size_t)(b * 4 + hg) * NPAD + n) * 32 + d] = (_Float16)0.f;
        return;
    }
    int seg, base;
    const float* w = nullptr;
    _Float16* dst;
    if (u < 2048)        { seg = 0; base = u;          w = Wq;   dst = (_Float16*)(ws + OFF_WFQ); }
    else if (u < 4096)   { seg = 0; base = u - 2048;   w = kv1;  dst = (_Float16*)(ws + OFF_WFKV1); }
    else if (u < 6144)   { seg = 0; base = u - 4096;   w = kv2;  dst = (_Float16*)(ws + OFF_WFKV2); }
    else if (u < 8192)   { seg = 0; base = u - 6144;   w = proj; dst = (_Float16*)(ws + OFF_WFPROJ); }
    else if (u < 40960)  { seg = 1; base = u - 8192;   w = sr1w; dst = (_Float16*)(ws + OFF_WFSR1); }
    else                 { seg = 2; base = u - 40960;  w = sr2w; dst = (_Float16*)(ws + OFF_WFSR2); }
    int lane = base & 63;
    int t = (base >> 6) & 7;
    int kc = base >> 9;
    int n = t * 16 + (lane & 15);
    int k0 = kc * 32 + (lane >> 4) * 8;
    half8v val;
    #pragma unroll
    for (int j = 0; j < 8; ++j) {
        int k = k0 + j;
        float v;
        if (seg == 0) v = w[n * 128 + k];
        else if (seg == 1) v = w[(n * 128 + (k & 127)) * 16 + (k >> 7)];
        else v = w[(n * 128 + (k & 127)) * 4 + (k >> 7)];
        val[j] = (_Float16)v;
    }
    *(half8v*)(dst + (size_t)base * 8) = val;
}

// ---------------- SR partial gemm (fused im2col gather), K-slice per wave ----------------
template<int S, int WR, int LL, int LM, int KW>
__device__ __forceinline__ void sr_partial(
    int mtile, int kcbase, int lane, const float* __restrict__ x,
    const float* __restrict__ msg, const _Float16* __restrict__ Wf, f32x4 acc[8]) {
    int m15 = lane & 15, quadk = lane >> 4;
    int m = mtile * 16 + m15;
    bool valid = m < BB * LM;
    const float* base = x;
    bool isimg = false;
    if (valid) {
        int b = m / LM, tok = m - b * LM;
        if (tok < LL) {
            int hr = tok / WR, wr = tok - hr * WR;
            base = x + ((size_t)b * N0 + hr * S * IMG + wr * S) * 128;
            isimg = true;
        } else {
            base = msg + ((size_t)b * MSGN + (tok - LL)) * 128;
        }
    }
    const half8v* Bp = (const half8v*)Wf + lane;
    for (int kk = 0; kk < KW; ++kk) {
        int kc = kcbase + kk;
        int k0 = (kc * 4 + quadk) * 8;
        int c = k0 & 127, ij = k0 >> 7;
        half8v a;
        if (valid) {
            int off;
            if (isimg) {
                int ki = ij / S, kj = ij - ki * S;
                off = (ki * IMG + kj) * 128 + c;
            } else off = c;
            const float4* p4 = (const float4*)(base + off);
            float4 f0 = p4[0], f1 = p4[1];
            a[0] = (_Float16)f0.x; a[1] = (_Float16)f0.y; a[2] = (_Float16)f0.z; a[3] = (_Float16)f0.w;
            a[4] = (_Float16)f1.x; a[5] = (_Float16)f1.y; a[6] = (_Float16)f1.z; a[7] = (_Float16)f1.w;
        } else {
            #pragma unroll
            for (int j = 0; j < 8; ++j) a[j] = (_Float16)0.f;
        }
        #pragma unroll
        for (int t = 0; t < 8; ++t)
            acc[t] = __builtin_amdgcn_mfma_f32_16x16x32_f16(a, Bp[(size_t)(kc * 8 + t) * 64], acc[t], 0, 0, 0);
    }
}

// ---------------- fused: SR gemms (split-K x4, LN+GELU) [0,646) + q projection [646,1159) ----------------
__global__ __launch_bounds__(256) void input_gemms(
    const float* __restrict__ x, const float* __restrict__ msg,
    const _Float16* __restrict__ Wf1, const _Float16* __restrict__ Wf2,
    const float* __restrict__ b1, const float* __restrict__ g1, const float* __restrict__ be1,
    const float* __restrict__ b2, const float* __restrict__ g2, const float* __restrict__ be2,
    _Float16* __restrict__ XK1, _Float16* __restrict__ XK2,
    const _Float16* __restrict__ WfQ, const float* __restrict__ bq,
    _Float16* __restrict__ Qh) {
    __shared__ float red[4][2048];
    int tid = threadIdx.x;
    int lane = tid & 63, wave = tid >> 6;
    int bid = blockIdx.x;

    if (bid >= 646) {
        // ---- q projection path (direct x/msg gather, K=128) ----
        int mt = (bid - 646) * 4 + wave;
        int m15 = lane & 15, quadk = lane >> 4;
        int m = mt * 16 + m15;
        bool valid = m < BB * NTOT;
        const float* rowp = x;
        if (valid) {
            int b = m / NTOT, n = m - b * NTOT;
            rowp = (n < N0) ? (x + ((size_t)b * N0 + n) * 128)
                            : (msg + ((size_t)b * MSGN + (n - N0)) * 128);
        }
        const half8v* Bp = (const half8v*)WfQ + lane;
        f32x4 acc[8];
        #pragma unroll
        for (int t = 0; t < 8; ++t) acc[t] = (f32x4){0.f, 0.f, 0.f, 0.f};
        #pragma unroll
        for (int kc = 0; kc < 4; ++kc) {
            half8v a;
            if (valid) {
                const float4* p4 = (const float4*)(rowp + (kc * 4 + quadk) * 8);
                float4 f0 = p4[0], f1 = p4[1];
                a[0] = (_Float16)f0.x; a[1] = (_Float16)f0.y; a[2] = (_Float16)f0.z; a[3] = (_Float16)f0.w;
                a[4] = (_Float16)f1.x; a[5] = (_Float16)f1.y; a[6] = (_Float16)f1.z; a[7] = (_Float16)f1.w;
            } else {
                #pragma unroll
                for (int j = 0; j < 8; ++j) a[j] = (_Float16)0.f;
            }
            #pragma unroll
            for (int t = 0; t < 8; ++t)
                acc[t] = __builtin_amdgcn_mfma_f32_16x16x32_f16(a, Bp[(size_t)(kc * 8 + t) * 64], acc[t], 0, 0, 0);
        }
        int quad = lane >> 4, n15 = lane & 15;
        // 1/sqrt(32) * log2(e): attn uses exp2 directly on the scores
        const float qscale = 0.17677669529663687f * 1.4426950408889634f;
        #pragma unroll
        for (int r = 0; r < 4; ++r) {
            int mm = mt * 16 + quad * 4 + r;
            if (mm >= BB * NTOT) continue;
            int b = mm / NTOT, tok = mm - b * NTOT;
            #pragma unroll
            for (int t = 0; t < 8; ++t) {
                int n = t * 16 + n15;
                Qh[((size_t)(b * 4 + (n >> 5)) * NPAD + tok) * 32 + (n & 31)] =
                    (_Float16)((acc[t][r] + bq[n]) * qscale);
            }
        }
        return;
    }

    // ---- SR path: split-K x4 per m-tile, LDS reduce, LN+GELU ----
    f32x4 acc[8];
    #pragma unroll
    for (int t = 0; t < 8; ++t) acc[t] = (f32x4){0.f, 0.f, 0.f, 0.f};
    const float* bias;
    const float* lng;
    const float* lnb;
    _Float16* outp;
    int mtile, Mv;
    if (bid < 132) {
        mtile = bid; Mv = 2080;
        sr_partial<4, 16, 256, 260, 16>(mtile, wave * 16, lane, x, msg, Wf1, acc);
        bias = b1; lng = g1; lnb = be1; outp = XK1;
    } else {
        mtile = bid - 132; Mv = 8224;
        sr_partial<2, 32, 1024, 1028, 4>(mtile, wave * 4, lane, x, msg, Wf2, acc);
        bias = b2; lng = g2; lnb = be2; outp = XK2;
    }
    int quad = lane >> 4, n15 = lane & 15;
    #pragma unroll
    for (int t = 0; t < 8; ++t)
        #pragma unroll
        for (int r = 0; r < 4; ++r)
            red[wave][(quad * 4 + r) * 128 + t * 16 + n15] = acc[t][r];
    __syncthreads();
    for (int e = tid; e < 2048; e += 256)
        red[0][e] = red[0][e] + red[1][e] + red[2][e] + red[3][e];
    __syncthreads();
    int r16 = tid >> 4, l16 = tid & 15;
    int m = mtile * 16 + r16;
    float v[8];
    float s = 0.f;
    #pragma unroll
    for (int j = 0; j < 8; ++j) { v[j] = red[0][r16 * 128 + j * 16 + l16] + bias[j * 16 + l16]; s += v[j]; }
    #pragma unroll
    for (int off = 1; off < 16; off <<= 1) s += __shfl_xor(s, off);
    float mu = s * (1.f / 128.f);
    float q = 0.f;
    #pragma unroll
    for (int j = 0; j < 8; ++j) { v[j] -= mu; q += v[j] * v[j]; }
    #pragma unroll
    for (int off = 1; off < 16; off <<= 1) q += __shfl_xor(q, off);
    float rs = rsqrtf(q * (1.f / 128.f) + 1e-5f);
    if (m < Mv) {
        #pragma unroll
        for (int j = 0; j < 8; ++j) {
            int n = j * 16 + l16;
            float y = v[j] * rs * lng[n] + lnb[n];
            y = 0.5f * y * (1.f + erff(y * 0.70710678118654752f));
            outp[af_idx(m, n, 4)] = (_Float16)y;
        }
    }
}

// ---------------- merged KV gemm (both branches) ----------------
__global__ __launch_bounds__(256) void kv_gemm(
    const _Float16* __restrict__ XK1, const _Float16* __restrict__ XK2,
    const _Float16* __restrict__ Wf1, const _Float16* __restrict__ Wf2,
    const float* __restrict__ b1, const float* __restrict__ b2,
    float* __restrict__ o1, float* __restrict__ o2) {
    int lane = threadIdx.x & 63, wave = threadIdx.x >> 6;
    int t = blockIdx.x * 4 + wave;
    int lt;
    const half8v* Ap;
    const half8v* Bp;
    const float* bias;
    float* outp;
    if (t < 130) { lt = t;       Ap = (const half8v*)XK1 + (size_t)lt * 4 * 64 + lane; Bp = (const half8v*)Wf1 + lane; bias = b1; outp = o1; }
    else         { lt = t - 130; Ap = (const half8v*)XK2 + (size_t)lt * 4 * 64 + lane; Bp = (const half8v*)Wf2 + lane; bias = b2; outp = o2; }
    f32x4 acc[8];
    #pragma unroll
    for (int tt = 0; tt < 8; ++tt) acc[tt] = (f32x4){0.f, 0.f, 0.f, 0.f};
    #pragma unroll
    for (int kc = 0; kc < 4; ++kc) {
        half8v a = Ap[(size_t)kc * 64];
        #pragma unroll
        for (int tt = 0; tt < 8; ++tt)
            acc[tt] = __builtin_amdgcn_mfma_f32_16x16x32_f16(a, Bp[(size_t)(kc * 8 + tt) * 64], acc[tt], 0, 0, 0);
    }
    int quad = lane >> 4, n15 = lane & 15;
    #pragma unroll
    for (int r = 0; r < 4; ++r) {
        int m = lt * 16 + quad * 4 + r;
        #pragma unroll
        for (int tt = 0; tt < 8; ++tt)
            outp[(size_t)m * 128 + tt * 16 + n15] = acc[tt][r] + bias[tt * 16 + n15];
    }
}

// ---------------- merged V-fixup + fp16 pack (both branches) ----------------
// Vt layout: [b,h2][key>>2][d16:16][dhalf:2][key&3] so a lane's PV B-frag
// (both d-halves) is one contiguous 16B load in attn.
__global__ void pack_kv(const float* __restrict__ kv1o, const float* __restrict__ kv2o,
                        const float* __restrict__ lc1w, const float* __restrict__ lc1b,
                        const float* __restrict__ lc2w, const float* __restrict__ lc2b,
                        _Float16* __restrict__ Kh1, _Float16* __restrict__ Vt1,
                        _Float16* __restrict__ Kh2, _Float16* __restrict__ Vt2) {
    int idx = blockIdx.x * 256 + threadIdx.x;
    const int T1 = BB * LMP1 * 64;
    const float* kv;
    const float* lcw;
    const float* lcb;
    _Float16* Kh;
    _Float16* Vt;
    int Wr, L, Lm, Lmp, li;
    if (idx < T1) { li = idx;      kv = kv1o; lcw = lc1w; lcb = lc1b; Kh = Kh1; Vt = Vt1; Wr = 16; L = 256;  Lm = 260;  Lmp = LMP1; }
    else          { li = idx - T1; kv = kv2o; lcw = lc2w; lcb = lc2b; Kh = Kh2; Vt = Vt2; Wr = 32; L = 1024; Lm = 1028; Lmp = LMP2; }
    int ch = li & 63;
    int rest = li >> 6;
    int n = rest % Lmp;
    int b = rest / Lmp;
    int h2 = ch >> 5, d = ch & 31;
    int Hr = L / Wr;
    float kval = 0.f, vnew = 0.f;
    if (n < Lm) {
        const float* kvb = kv + (size_t)b * Lm * 128;
        kval = kvb[(size_t)n * 128 + ch];
        float v = kvb[(size_t)n * 128 + 64 + ch];
        float add;
        if (n < L) {
            int hr = n / Wr, wr = n - hr * Wr;
            float sum = lcb[ch];
            #pragma unroll
            for (int ki = 0; ki < 3; ++ki)
                #pragma unroll
                for (int kj = 0; kj < 3; ++kj) {
                    int y = hr + ki - 1, xx = wr + kj - 1;
                    if ((unsigned)y < (unsigned)Hr && (unsigned)xx < (unsigned)Wr)
                        sum += lcw[ch * 9 + ki * 3 + kj] * kvb[((size_t)y * Wr + xx) * 128 + 64 + ch];
                }
            add = sum;
        } else {
            add = v;   // msg tokens: v_add = v => v_new = 2v
        }
        vnew = v + add;
    }
    Kh[((size_t)(b * 2 + h2) * Lmp + n) * 32 + d] = (_Float16)kval;
    Vt[(size_t)(b * 2 + h2) * Lmp * 32 + (size_t)(n >> 2) * 128
       + (d & 15) * 8 + ((d >> 4) << 2) + (n & 3)] = (_Float16)vnew;
}

// ---------------- flash attention: full key range per wave, in-kernel normalization ----------------
// z = (br,h2): br=1 (1088 keys) dispatched first, br=0 (320 keys) backfills.
// No split-K: l is complete per wave -> O normalized in-register, stored fp16 once.
// Pad keys (60 per branch) have K=0 -> p=1 -> subtract 60 from l; V=0 so O unaffected.
// Pad q-rows have Q=0 -> finite l; stores guarded by n<NTOT.
__global__ __launch_bounds__(128, 8) void attn_mfma(
    const _Float16* __restrict__ Qh,
    const _Float16* __restrict__ Kh1, const _Float16* __restrict__ Vt1,
    const _Float16* __restrict__ Kh2, const _Float16* __restrict__ Vt2,
    _Float16* __restrict__ XP) {
    int tid = threadIdx.x;
    int lane = tid & 63, wave = tid >> 6;
    int b = blockIdx.y;
    int z = blockIdx.z;
    int h2 = z & 1, br = 1 - (z >> 1);
    int tile = blockIdx.x * 2 + wave;       // 0..129
    int n0 = tile * 32;
    int q16 = lane & 15, quad = lane >> 4;
    const f32x4 zf = {0.f, 0.f, 0.f, 0.f};
    int Lmp  = br ? LMP2 : LMP1;
    int k_hi = Lmp;                          // full padded range
    const _Float16* kb = (br ? Kh2 : Kh1) + (size_t)(b * 2 + h2) * Lmp * 32;
    const _Float16* vb = (br ? Vt2 : Vt1) + (size_t)(b * 2 + h2) * Lmp * 32;
    int hg = br * 2 + h2;
    const _Float16* qp = Qh + ((size_t)(b * 4 + hg) * NPAD + n0 + q16) * 32 + quad * 8;
    half8v qf0 = *(const half8v*)qp;
    half8v qf1 = *(const half8v*)(qp + 512);   // +16 rows
    f32x4 O00 = zf, O01 = zf, O10 = zf, O11 = zf;
    float la = 0.f, lb = 0.f;

    // prime K double-buffer
    half8v kf[4];
    #pragma unroll
    for (int i = 0; i < 4; ++i)
        kf[i] = *(const half8v*)(kb + (size_t)(i * 16 + q16) * 32 + quad * 8);

    for (int k0 = 0; k0 < k_hi; k0 += 64) {
        // V for current block: one 16B load per i (both d-halves)
        half8v vv[4];
        #pragma unroll
        for (int i = 0; i < 4; ++i)
            vv[i] = *(const half8v*)(vb + (size_t)((k0 >> 2) + i * 4 + quad) * 128 + q16 * 8);
        // K for next block (stays in flight across the MFMAs below)
        int k0n = (k0 + 64 < k_hi) ? k0 + 64 : 0;
        half8v kn[4];
        #pragma unroll
        for (int i = 0; i < 4; ++i)
            kn[i] = *(const half8v*)(kb + (size_t)(k0n + i * 16 + q16) * 32 + quad * 8);

        // S = K·Q^T for both q-tiles, exp2 -> p (scores already log2-scaled)
        half4v p0[4], p1[4];
        #pragma unroll
        for (int i = 0; i < 4; ++i) {
            f32x4 s0 = __builtin_amdgcn_mfma_f32_16x16x32_f16(kf[i], qf0, zf, 0, 0, 0);
            f32x4 s1 = __builtin_amdgcn_mfma_f32_16x16x32_f16(kf[i], qf1, zf, 0, 0, 0);
            half4v a, c;
            #pragma unroll
            for (int r = 0; r < 4; ++r) {
                float e0 = exp2_fast(s0[r]); la += e0; a[r] = (_Float16)e0;
                float e1 = exp2_fast(s1[r]); lb += e1; c[r] = (_Float16)e1;
            }
            p0[i] = a; p1[i] = c;
        }
        // PV for both q-tiles
        #pragma unroll
        for (int i = 0; i < 4; ++i) {
            half4v v0 = __builtin_shufflevector(vv[i], vv[i], 0, 1, 2, 3);
            half4v v1 = __builtin_shufflevector(vv[i], vv[i], 4, 5, 6, 7);
            O00 = __builtin_amdgcn_mfma_f32_16x16x16f16(p0[i], v0, O00, 0, 0, 0);
            O01 = __builtin_amdgcn_mfma_f32_16x16x16f16(p0[i], v1, O01, 0, 0, 0);
            O10 = __builtin_amdgcn_mfma_f32_16x16x16f16(p1[i], v0, O10, 0, 0, 0);
            O11 = __builtin_amdgcn_mfma_f32_16x16x16f16(p1[i], v1, O11, 0, 0, 0);
        }
        #pragma unroll
        for (int i = 0; i < 4; ++i) kf[i] = kn[i];
    }

    // complete row sums (la/lb live in lanes with q16 = row index, all quads)
    la += __shfl_xor(la, 16); la += __shfl_xor(la, 32);
    lb += __shfl_xor(lb, 16); lb += __shfl_xor(lb, 32);
    la -= 60.0f; lb -= 60.0f;               // 60 pad keys per branch contribute p=1
    float ia = 1.0f / la;
    float ib = 1.0f / lb;

    // normalize + store: O rows are quad*4+r; row j's 1/l lives in lanes with (lane&15)==j
    int kbase = br * 64 + h2 * 32;
    #pragma unroll
    for (int r = 0; r < 4; ++r) {
        int row = quad * 4 + r;
        int src = (lane & 48) | row;
        float fa = __shfl(ia, src);
        float fb = __shfl(ib, src);
        int n = n0 + row;
        if (n < NTOT) {
            int m = b * NTOT + n;
            XP[af_idx(m, kbase + q16, 4)] = (_Float16)(O00[r] * fa);
            XP[af_idx(m, kbase + 16 + q16, 4)] = (_Float16)(O01[r] * fa);
        }
        int n2 = n + 16;
        if (n2 < NTOT) {
            int m = b * NTOT + n2;
            XP[af_idx(m, kbase + q16, 4)] = (_Float16)(O10[r] * fb);
            XP[af_idx(m, kbase + 16 + q16, 4)] = (_Float16)(O11[r] * fb);
        }
    }
}

// ---------------- final projection: XP (already normalized fp16) + residual ----------------
__global__ __launch_bounds__(256) void proj_gemm(
    const _Float16* __restrict__ XP,
    const _Float16* __restrict__ Wf, const float* __restrict__ bias,
    float* __restrict__ out_f32, const float* __restrict__ x, const float* __restrict__ msg) {
    int lane = threadIdx.x & 63, wave = threadIdx.x >> 6;
    int mt = blockIdx.x * 4 + wave;
    const half8v* Ap = (const half8v*)XP + (size_t)mt * 4 * 64 + lane;
    const half8v* Bp = (const half8v*)Wf + lane;
    f32x4 acc[8];
    #pragma unroll
    for (int t = 0; t < 8; ++t) acc[t] = (f32x4){0.f, 0.f, 0.f, 0.f};
    #pragma unroll
    for (int kc = 0; kc < 4; ++kc) {
        half8v a = Ap[(size_t)kc * 64];
        #pragma unroll
        for (int t = 0; t < 8; ++t)
            acc[t] = __builtin_amdgcn_mfma_f32_16x16x32_f16(a, Bp[(size_t)(kc * 8 + t) * 64], acc[t], 0, 0, 0);
    }
    int quad = lane >> 4, n15 = lane & 15;
    #pragma unroll
    for (int r = 0; r < 4; ++r) {
        int m = mt * 16 + quad * 4 + r;
        if (m >= BB * NTOT) continue;
        int b = m / NTOT, tok = m - b * NTOT;
        const float* rp;
        float* dst;
        if (tok < N0) {
            rp = x + ((size_t)b * N0 + tok) * 128;
            dst = out_f32 + ((size_t)b * N0 + tok) * 128;
        } else {
            rp = msg + ((size_t)b * MSGN + (tok - N0)) * 128;
            dst = out_f32 + (size_t)BB * N0 * 128 + ((size_t)b * MSGN + (tok - N0)) * 128;
        }
        #pragma unroll
        for (int t = 0; t < 8; ++t) {
            int n = t * 16 + n15;
            dst[n] = acc[t][r] + bias[n] + rp[n];
        }
    }
}

extern "C" void kernel_launch(void* const* d_in, const int* in_sizes, int n_in,
                              void* d_out, int out_size, void* d_ws, size_t ws_size,
                              hipStream_t stream) {
    const float* x     = (const float*)d_in[0];
    const float* msg   = (const float*)d_in[1];
    const float* Wq    = (const float*)d_in[2];
    const float* bq    = (const float*)d_in[3];
    const float* sr1w  = (const float*)d_in[4];
    const float* sr1b  = (const float*)d_in[5];
    const float* ln1g  = (const float*)d_in[6];
    const float* ln1b  = (const float*)d_in[7];
    const float* sr2w  = (const float*)d_in[8];
    const float* sr2b  = (const float*)d_in[9];
    const float* ln2g  = (const float*)d_in[10];
    const float* ln2b  = (const float*)d_in[11];
    const float* kv1w  = (const float*)d_in[12];
    const float* kv1b  = (const float*)d_in[13];
    const float* kv2w  = (const float*)d_in[14];
    const float* kv2b  = (const float*)d_in[15];
    const float* lc1w  = (const float*)d_in[16];
    const float* lc1b  = (const float*)d_in[17];
    const float* lc2w  = (const float*)d_in[18];
    const float* lc2b  = (const float*)d_in[19];
    const float* projw = (const float*)d_in[20];
    const float* projb = (const float*)d_in[21];
    float* ws  = (float*)d_ws;
    float* out = (float*)d_out;

    _Float16* WfQ    = (_Float16*)(ws + OFF_WFQ);
    _Float16* WfKV1  = (_Float16*)(ws + OFF_WFKV1);
    _Float16* WfKV2  = (_Float16*)(ws + OFF_WFKV2);
    _Float16* WfPROJ = (_Float16*)(ws + OFF_WFPROJ);
    _Float16* WfSR1  = (_Float16*)(ws + OFF_WFSR1);
    _Float16* WfSR2  = (_Float16*)(ws + OFF_WFSR2);
    _Float16* Qh     = (_Float16*)(ws + OFF_QH);
    _Float16* XP     = (_Float16*)(ws + OFF_XP);
    _Float16* XK1    = (_Float16*)(ws + OFF_XK1);
    _Float16* XK2    = (_Float16*)(ws + OFF_XK2);
    float* kv1o      = ws + OFF_KV1O;
    float* kv2o      = ws + OFF_KV2O;
    _Float16* Kh1    = (_Float16*)(ws + OFF_KH1);
    _Float16* Vt1    = (_Float16*)(ws + OFF_VT1);
    _Float16* Kh2    = (_Float16*)(ws + OFF_KH2);
    _Float16* Vt2    = (_Float16*)(ws + OFF_VT2);

    // 1. weights swizzle + Q pad zero (49152 weight threads + 61440 pad threads)
    prep_weights<<<432, 256, 0, stream>>>(Wq, kv1w, kv2w, projw, sr1w, sr2w, ws, Qh);
    // 2. fused SR convs (split-K x4, LN+GELU) + q projection
    input_gemms<<<1159, 256, 0, stream>>>(x, msg, WfSR1, WfSR2,
                                          sr1b, ln1g, ln1b, sr2b, ln2g, ln2b,
                                          XK1, XK2, WfQ, bq, Qh);
    // 3. KV projections, both branches
    kv_gemm<<<161, 256, 0, stream>>>(XK1, XK2, WfKV1, WfKV2, kv1b, kv2b, kv1o, kv2o);
    // 4. V fixup + pack, both branches
    pack_kv<<<2816, 256, 0, stream>>>(kv1o, kv2o, lc1w, lc1b, lc2w, lc2b,
                                      Kh1, Vt1, Kh2, Vt2);
    // 5. flash attention: full key range per wave, normalized output
    attn_mfma<<<dim3(65, 8, 4), 128, 0, stream>>>(Qh, Kh1, Vt1, Kh2, Vt2, XP);
    // 6. final projection + residual
    proj_gemm<<<513, 256, 0, stream>>>(XP, WfPROJ, projb, out, x, msg);
}

// Round 3
// 190.988 us; speedup vs baseline: 1.1838x; 1.1838x over previous
//
#include <hip/hip_runtime.h>
#include <math.h>

#define BB 8
#define CC 128
#define N0 4096
#define MSGN 4
#define NTOT 4100
#define IMG 64
#define NPAD 4224            // 132 tiles of 32 q-rows = 33 blocks x 4 waves exactly
#define LMP1 320
#define LMP2 1088

// ---------------- workspace layout (float indices) ----------------
#define OFF_WFQ    0
#define OFF_WFKV1  8192
#define OFF_WFKV2  16384
#define OFF_WFPROJ 24576
#define OFF_WFSR1  32768        // K=2048: 131072 f
#define OFF_WFSR2  163840       // K=512:  32768 f
#define OFF_QH     196608       // fp16 8*4*4224*32 = 4325376 h = 2162688 f -> end 2359296
#define OFF_XK1    2359296      // 133120 f (dead after kv_gemm)
#define OFF_XK2    2492416      // 526336 f (dead after kv_gemm)
#define OFF_KV1O   3018752      // 266240 f (dead after pack_kv)
#define OFF_KV2O   3284992      // 1052672 f (dead after pack_kv)
#define OFF_KH1    4337664      // 81920 f
#define OFF_VT1    4419584      // 81920 f  ([b,h2][key>>2][d16:16][dhalf][key&3])
#define OFF_KH2    4501504      // 278528 f
#define OFF_VT2    4780032      // 278528 f -> end 5058560
#define OFF_XP     5058560      // normalized attn O frags (fp16): 2101248 f -> end 7159808 (28.6 MB)

typedef _Float16 half8v __attribute__((ext_vector_type(8)));
typedef _Float16 half4v __attribute__((ext_vector_type(4)));
typedef float f32x4 __attribute__((ext_vector_type(4)));

__device__ __forceinline__ size_t af_idx(int m, int k, int Kc) {
    return ((size_t)((m >> 4) * Kc + (k >> 5)) * 64 + ((k >> 3) & 3) * 16 + (m & 15)) * 8 + (k & 7);
}

// exp2 (scores carry log2e folded into Q scale)
__device__ __forceinline__ float exp2_fast(float x) {
#if __has_builtin(__builtin_amdgcn_exp2f)
    return __builtin_amdgcn_exp2f(x);
#else
    return __expf(x * 0.6931471805599453f);
#endif
}

// async global->LDS, 16B per lane; LDS dest = uniform base + lane*16
__device__ __forceinline__ void gload16(const _Float16* g, _Float16* l) {
    __builtin_amdgcn_global_load_lds(
        (const __attribute__((address_space(1))) unsigned int*)g,
        (__attribute__((address_space(3))) unsigned int*)l, 16, 0, 0);
}

// ---------------- weight prep (B-frag swizzle) + Q-pad zero ----------------
__global__ void prep_weights(const float* __restrict__ Wq, const float* __restrict__ kv1,
                             const float* __restrict__ kv2, const float* __restrict__ proj,
                             const float* __restrict__ sr1w, const float* __restrict__ sr2w,
                             float* __restrict__ ws, _Float16* __restrict__ Qh) {
    int u = blockIdx.x * blockDim.x + threadIdx.x;
    if (u >= 49152) {
        int idx = u - 49152;
        if (idx >= BB * 4 * (NPAD - NTOT) * 32) return;
        int d = idx & 31;
        int rest = idx >> 5;
        int n = NTOT + rest % (NPAD - NTOT);
        int rest2 = rest / (NPAD - NTOT);
        int hg = rest2 & 3;
        int b = rest2 >> 2;
        Qh[((size_t)(b * 4 + hg) * NPAD + n) * 32 + d] = (_Float16)0.f;
        return;
    }
    int seg, base;
    const float* w = nullptr;
    _Float16* dst;
    if (u < 2048)        { seg = 0; base = u;          w = Wq;   dst = (_Float16*)(ws + OFF_WFQ); }
    else if (u < 4096)   { seg = 0; base = u - 2048;   w = kv1;  dst = (_Float16*)(ws + OFF_WFKV1); }
    else if (u < 6144)   { seg = 0; base = u - 4096;   w = kv2;  dst = (_Float16*)(ws + OFF_WFKV2); }
    else if (u < 8192)   { seg = 0; base = u - 6144;   w = proj; dst = (_Float16*)(ws + OFF_WFPROJ); }
    else if (u < 40960)  { seg = 1; base = u - 8192;   w = sr1w; dst = (_Float16*)(ws + OFF_WFSR1); }
    else                 { seg = 2; base = u - 40960;  w = sr2w; dst = (_Float16*)(ws + OFF_WFSR2); }
    int lane = base & 63;
    int t = (base >> 6) & 7;
    int kc = base >> 9;
    int n = t * 16 + (lane & 15);
    int k0 = kc * 32 + (lane >> 4) * 8;
    half8v val;
    #pragma unroll
    for (int j = 0; j < 8; ++j) {
        int k = k0 + j;
        float v;
        if (seg == 0) v = w[n * 128 + k];
        else if (seg == 1) v = w[(n * 128 + (k & 127)) * 16 + (k >> 7)];
        else v = w[(n * 128 + (k & 127)) * 4 + (k >> 7)];
        val[j] = (_Float16)v;
    }
    *(half8v*)(dst + (size_t)base * 8) = val;
}

// ---------------- SR partial gemm (fused im2col gather), K-slice per wave ----------------
template<int S, int WR, int LL, int LM, int KW>
__device__ __forceinline__ void sr_partial(
    int mtile, int kcbase, int lane, const float* __restrict__ x,
    const float* __restrict__ msg, const _Float16* __restrict__ Wf, f32x4 acc[8]) {
    int m15 = lane & 15, quadk = lane >> 4;
    int m = mtile * 16 + m15;
    bool valid = m < BB * LM;
    const float* base = x;
    bool isimg = false;
    if (valid) {
        int b = m / LM, tok = m - b * LM;
        if (tok < LL) {
            int hr = tok / WR, wr = tok - hr * WR;
            base = x + ((size_t)b * N0 + hr * S * IMG + wr * S) * 128;
            isimg = true;
        } else {
            base = msg + ((size_t)b * MSGN + (tok - LL)) * 128;
        }
    }
    const half8v* Bp = (const half8v*)Wf + lane;
    for (int kk = 0; kk < KW; ++kk) {
        int kc = kcbase + kk;
        int k0 = (kc * 4 + quadk) * 8;
        int c = k0 & 127, ij = k0 >> 7;
        half8v a;
        if (valid) {
            int off;
            if (isimg) {
                int ki = ij / S, kj = ij - ki * S;
                off = (ki * IMG + kj) * 128 + c;
            } else off = c;
            const float4* p4 = (const float4*)(base + off);
            float4 f0 = p4[0], f1 = p4[1];
            a[0] = (_Float16)f0.x; a[1] = (_Float16)f0.y; a[2] = (_Float16)f0.z; a[3] = (_Float16)f0.w;
            a[4] = (_Float16)f1.x; a[5] = (_Float16)f1.y; a[6] = (_Float16)f1.z; a[7] = (_Float16)f1.w;
        } else {
            #pragma unroll
            for (int j = 0; j < 8; ++j) a[j] = (_Float16)0.f;
        }
        #pragma unroll
        for (int t = 0; t < 8; ++t)
            acc[t] = __builtin_amdgcn_mfma_f32_16x16x32_f16(a, Bp[(size_t)(kc * 8 + t) * 64], acc[t], 0, 0, 0);
    }
}

// ---------------- fused: SR gemms (split-K x4, LN+GELU) [0,646) + q projection [646,1159) ----------------
__global__ __launch_bounds__(256) void input_gemms(
    const float* __restrict__ x, const float* __restrict__ msg,
    const _Float16* __restrict__ Wf1, const _Float16* __restrict__ Wf2,
    const float* __restrict__ b1, const float* __restrict__ g1, const float* __restrict__ be1,
    const float* __restrict__ b2, const float* __restrict__ g2, const float* __restrict__ be2,
    _Float16* __restrict__ XK1, _Float16* __restrict__ XK2,
    const _Float16* __restrict__ WfQ, const float* __restrict__ bq,
    _Float16* __restrict__ Qh) {
    __shared__ float red[4][2048];
    int tid = threadIdx.x;
    int lane = tid & 63, wave = tid >> 6;
    int bid = blockIdx.x;

    if (bid >= 646) {
        // ---- q projection path (direct x/msg gather, K=128) ----
        int mt = (bid - 646) * 4 + wave;
        int m15 = lane & 15, quadk = lane >> 4;
        int m = mt * 16 + m15;
        bool valid = m < BB * NTOT;
        const float* rowp = x;
        if (valid) {
            int b = m / NTOT, n = m - b * NTOT;
            rowp = (n < N0) ? (x + ((size_t)b * N0 + n) * 128)
                            : (msg + ((size_t)b * MSGN + (n - N0)) * 128);
        }
        const half8v* Bp = (const half8v*)WfQ + lane;
        f32x4 acc[8];
        #pragma unroll
        for (int t = 0; t < 8; ++t) acc[t] = (f32x4){0.f, 0.f, 0.f, 0.f};
        #pragma unroll
        for (int kc = 0; kc < 4; ++kc) {
            half8v a;
            if (valid) {
                const float4* p4 = (const float4*)(rowp + (kc * 4 + quadk) * 8);
                float4 f0 = p4[0], f1 = p4[1];
                a[0] = (_Float16)f0.x; a[1] = (_Float16)f0.y; a[2] = (_Float16)f0.z; a[3] = (_Float16)f0.w;
                a[4] = (_Float16)f1.x; a[5] = (_Float16)f1.y; a[6] = (_Float16)f1.z; a[7] = (_Float16)f1.w;
            } else {
                #pragma unroll
                for (int j = 0; j < 8; ++j) a[j] = (_Float16)0.f;
            }
            #pragma unroll
            for (int t = 0; t < 8; ++t)
                acc[t] = __builtin_amdgcn_mfma_f32_16x16x32_f16(a, Bp[(size_t)(kc * 8 + t) * 64], acc[t], 0, 0, 0);
        }
        int quad = lane >> 4, n15 = lane & 15;
        // 1/sqrt(32) * log2(e): attn uses exp2 directly on the scores
        const float qscale = 0.17677669529663687f * 1.4426950408889634f;
        #pragma unroll
        for (int r = 0; r < 4; ++r) {
            int mm = mt * 16 + quad * 4 + r;
            if (mm >= BB * NTOT) continue;
            int b = mm / NTOT, tok = mm - b * NTOT;
            #pragma unroll
            for (int t = 0; t < 8; ++t) {
                int n = t * 16 + n15;
                Qh[((size_t)(b * 4 + (n >> 5)) * NPAD + tok) * 32 + (n & 31)] =
                    (_Float16)((acc[t][r] + bq[n]) * qscale);
            }
        }
        return;
    }

    // ---- SR path: split-K x4 per m-tile, LDS reduce, LN+GELU ----
    f32x4 acc[8];
    #pragma unroll
    for (int t = 0; t < 8; ++t) acc[t] = (f32x4){0.f, 0.f, 0.f, 0.f};
    const float* bias;
    const float* lng;
    const float* lnb;
    _Float16* outp;
    int mtile, Mv;
    if (bid < 132) {
        mtile = bid; Mv = 2080;
        sr_partial<4, 16, 256, 260, 16>(mtile, wave * 16, lane, x, msg, Wf1, acc);
        bias = b1; lng = g1; lnb = be1; outp = XK1;
    } else {
        mtile = bid - 132; Mv = 8224;
        sr_partial<2, 32, 1024, 1028, 4>(mtile, wave * 4, lane, x, msg, Wf2, acc);
        bias = b2; lng = g2; lnb = be2; outp = XK2;
    }
    int quad = lane >> 4, n15 = lane & 15;
    #pragma unroll
    for (int t = 0; t < 8; ++t)
        #pragma unroll
        for (int r = 0; r < 4; ++r)
            red[wave][(quad * 4 + r) * 128 + t * 16 + n15] = acc[t][r];
    __syncthreads();
    for (int e = tid; e < 2048; e += 256)
        red[0][e] = red[0][e] + red[1][e] + red[2][e] + red[3][e];
    __syncthreads();
    int r16 = tid >> 4, l16 = tid & 15;
    int m = mtile * 16 + r16;
    float v[8];
    float s = 0.f;
    #pragma unroll
    for (int j = 0; j < 8; ++j) { v[j] = red[0][r16 * 128 + j * 16 + l16] + bias[j * 16 + l16]; s += v[j]; }
    #pragma unroll
    for (int off = 1; off < 16; off <<= 1) s += __shfl_xor(s, off);
    float mu = s * (1.f / 128.f);
    float q = 0.f;
    #pragma unroll
    for (int j = 0; j < 8; ++j) { v[j] -= mu; q += v[j] * v[j]; }
    #pragma unroll
    for (int off = 1; off < 16; off <<= 1) q += __shfl_xor(q, off);
    float rs = rsqrtf(q * (1.f / 128.f) + 1e-5f);
    if (m < Mv) {
        #pragma unroll
        for (int j = 0; j < 8; ++j) {
            int n = j * 16 + l16;
            float y = v[j] * rs * lng[n] + lnb[n];
            y = 0.5f * y * (1.f + erff(y * 0.70710678118654752f));
            outp[af_idx(m, n, 4)] = (_Float16)y;
        }
    }
}

// ---------------- merged KV gemm (both branches) ----------------
__global__ __launch_bounds__(256) void kv_gemm(
    const _Float16* __restrict__ XK1, const _Float16* __restrict__ XK2,
    const _Float16* __restrict__ Wf1, const _Float16* __restrict__ Wf2,
    const float* __restrict__ b1, const float* __restrict__ b2,
    float* __restrict__ o1, float* __restrict__ o2) {
    int lane = threadIdx.x & 63, wave = threadIdx.x >> 6;
    int t = blockIdx.x * 4 + wave;
    int lt;
    const half8v* Ap;
    const half8v* Bp;
    const float* bias;
    float* outp;
    if (t < 130) { lt = t;       Ap = (const half8v*)XK1 + (size_t)lt * 4 * 64 + lane; Bp = (const half8v*)Wf1 + lane; bias = b1; outp = o1; }
    else         { lt = t - 130; Ap = (const half8v*)XK2 + (size_t)lt * 4 * 64 + lane; Bp = (const half8v*)Wf2 + lane; bias = b2; outp = o2; }
    f32x4 acc[8];
    #pragma unroll
    for (int tt = 0; tt < 8; ++tt) acc[tt] = (f32x4){0.f, 0.f, 0.f, 0.f};
    #pragma unroll
    for (int kc = 0; kc < 4; ++kc) {
        half8v a = Ap[(size_t)kc * 64];
        #pragma unroll
        for (int tt = 0; tt < 8; ++tt)
            acc[tt] = __builtin_amdgcn_mfma_f32_16x16x32_f16(a, Bp[(size_t)(kc * 8 + tt) * 64], acc[tt], 0, 0, 0);
    }
    int quad = lane >> 4, n15 = lane & 15;
    #pragma unroll
    for (int r = 0; r < 4; ++r) {
        int m = lt * 16 + quad * 4 + r;
        #pragma unroll
        for (int tt = 0; tt < 8; ++tt)
            outp[(size_t)m * 128 + tt * 16 + n15] = acc[tt][r] + bias[tt * 16 + n15];
    }
}

// ---------------- merged V-fixup + fp16 pack (both branches) ----------------
// Vt layout: [b,h2][key>>2][d16:16][dhalf:2][key&3] so a lane's PV B-frag
// (both d-halves) is one contiguous 16B load.
__global__ void pack_kv(const float* __restrict__ kv1o, const float* __restrict__ kv2o,
                        const float* __restrict__ lc1w, const float* __restrict__ lc1b,
                        const float* __restrict__ lc2w, const float* __restrict__ lc2b,
                        _Float16* __restrict__ Kh1, _Float16* __restrict__ Vt1,
                        _Float16* __restrict__ Kh2, _Float16* __restrict__ Vt2) {
    int idx = blockIdx.x * 256 + threadIdx.x;
    const int T1 = BB * LMP1 * 64;
    const float* kv;
    const float* lcw;
    const float* lcb;
    _Float16* Kh;
    _Float16* Vt;
    int Wr, L, Lm, Lmp, li;
    if (idx < T1) { li = idx;      kv = kv1o; lcw = lc1w; lcb = lc1b; Kh = Kh1; Vt = Vt1; Wr = 16; L = 256;  Lm = 260;  Lmp = LMP1; }
    else          { li = idx - T1; kv = kv2o; lcw = lc2w; lcb = lc2b; Kh = Kh2; Vt = Vt2; Wr = 32; L = 1024; Lm = 1028; Lmp = LMP2; }
    int ch = li & 63;
    int rest = li >> 6;
    int n = rest % Lmp;
    int b = rest / Lmp;
    int h2 = ch >> 5, d = ch & 31;
    int Hr = L / Wr;
    float kval = 0.f, vnew = 0.f;
    if (n < Lm) {
        const float* kvb = kv + (size_t)b * Lm * 128;
        kval = kvb[(size_t)n * 128 + ch];
        float v = kvb[(size_t)n * 128 + 64 + ch];
        float add;
        if (n < L) {
            int hr = n / Wr, wr = n - hr * Wr;
            float sum = lcb[ch];
            #pragma unroll
            for (int ki = 0; ki < 3; ++ki)
                #pragma unroll
                for (int kj = 0; kj < 3; ++kj) {
                    int y = hr + ki - 1, xx = wr + kj - 1;
                    if ((unsigned)y < (unsigned)Hr && (unsigned)xx < (unsigned)Wr)
                        sum += lcw[ch * 9 + ki * 3 + kj] * kvb[((size_t)y * Wr + xx) * 128 + 64 + ch];
                }
            add = sum;
        } else {
            add = v;   // msg tokens: v_add = v => v_new = 2v
        }
        vnew = v + add;
    }
    Kh[((size_t)(b * 2 + h2) * Lmp + n) * 32 + d] = (_Float16)kval;
    Vt[(size_t)(b * 2 + h2) * Lmp * 32 + (size_t)(n >> 2) * 128
       + (d & 15) * 8 + ((d >> 4) << 2) + (n & 3)] = (_Float16)vnew;
}

// ---------------- flash attention: LDS-staged K/V shared by 4 waves ----------------
// Block: 4 waves = 4 q-tiles of 32 rows, same (b, h2, br). K/V 64-key tiles staged
// cooperatively into double-buffered LDS via global_load_lds (K fragment-permuted
// on the GLOBAL source side; LDS dest linear -> conflict-free ds_read_b128).
// No split-K: l complete per wave -> normalize in-register, store fp16 once.
// Pad keys (60/branch): K=0 -> p=1 -> l -= 60; V=0 so O unaffected.
__global__ __launch_bounds__(256, 4) void attn_mfma(
    const _Float16* __restrict__ Qh,
    const _Float16* __restrict__ Kh1, const _Float16* __restrict__ Vt1,
    const _Float16* __restrict__ Kh2, const _Float16* __restrict__ Vt2,
    _Float16* __restrict__ XP) {
    __shared__ _Float16 sK[2][2048];
    __shared__ _Float16 sV[2][2048];
    int tid = threadIdx.x;
    int lane = tid & 63, wave = tid >> 6;
    int b = blockIdx.y;
    int z = blockIdx.z;
    int h2 = z & 1, br = 1 - (z >> 1);     // long blocks (br=1) dispatch first
    int tile = blockIdx.x * 4 + wave;      // 0..131, all valid (NPAD=4224)
    int n0 = tile * 32;
    int q16 = lane & 15, quad = lane >> 4;
    const f32x4 zf = {0.f, 0.f, 0.f, 0.f};
    int NT = br ? (LMP2 / 64) : (LMP1 / 64);
    int Lmp = br ? LMP2 : LMP1;
    const _Float16* kb = (br ? Kh2 : Kh1) + (size_t)(b * 2 + h2) * Lmp * 32;
    const _Float16* vb = (br ? Vt2 : Vt1) + (size_t)(b * 2 + h2) * Lmp * 32;
    int hg = br * 2 + h2;
    const _Float16* qp = Qh + ((size_t)(b * 4 + hg) * NPAD + n0 + q16) * 32 + quad * 8;
    half8v qf0 = *(const half8v*)qp;
    half8v qf1 = *(const half8v*)(qp + 512);   // +16 rows
    f32x4 O00 = zf, O01 = zf, O10 = zf, O11 = zf;
    float la = 0.f, lb = 0.f;

    // per-lane staging source offsets within a 64-key tile (2048 halfs).
    // K: LDS slot j holds K[key = (j&15) + 16*subtile][d = (j>>4)*8..+7] -> permuted source.
    // V: tile is already fragment-linear in Vt -> linear source.
    int ksrc = (wave * 16 + q16) * 32 + quad * 8;
    int vsrc = wave * 512 + lane * 8;

    gload16(kb + ksrc, &sK[0][wave * 512]);
    gload16(vb + vsrc, &sV[0][wave * 512]);
    __syncthreads();                            // drains vmcnt before barrier

    for (int t = 0; t < NT; ++t) {
        int cur = t & 1;
        if (t + 1 < NT) {                       // stage next tile (async, overlaps compute)
            size_t o = (size_t)(t + 1) * 2048;
            gload16(kb + o + ksrc, &sK[cur ^ 1][wave * 512]);
            gload16(vb + o + vsrc, &sV[cur ^ 1][wave * 512]);
        }
        half8v kf[4], vv[4];
        #pragma unroll
        for (int i = 0; i < 4; ++i)
            kf[i] = *(const half8v*)&sK[cur][i * 512 + lane * 8];
        #pragma unroll
        for (int i = 0; i < 4; ++i)
            vv[i] = *(const half8v*)&sV[cur][i * 512 + quad * 128 + q16 * 8];

        // S = K·Q^T for both q-tiles, exp2 -> p (scores already log2-scaled)
        half4v p0[4], p1[4];
        #pragma unroll
        for (int i = 0; i < 4; ++i) {
            f32x4 s0 = __builtin_amdgcn_mfma_f32_16x16x32_f16(kf[i], qf0, zf, 0, 0, 0);
            f32x4 s1 = __builtin_amdgcn_mfma_f32_16x16x32_f16(kf[i], qf1, zf, 0, 0, 0);
            half4v a, c;
            #pragma unroll
            for (int r = 0; r < 4; ++r) {
                float e0 = exp2_fast(s0[r]); la += e0; a[r] = (_Float16)e0;
                float e1 = exp2_fast(s1[r]); lb += e1; c[r] = (_Float16)e1;
            }
            p0[i] = a; p1[i] = c;
        }
        // PV for both q-tiles
        #pragma unroll
        for (int i = 0; i < 4; ++i) {
            half4v v0 = __builtin_shufflevector(vv[i], vv[i], 0, 1, 2, 3);
            half4v v1 = __builtin_shufflevector(vv[i], vv[i], 4, 5, 6, 7);
            O00 = __builtin_amdgcn_mfma_f32_16x16x16f16(p0[i], v0, O00, 0, 0, 0);
            O01 = __builtin_amdgcn_mfma_f32_16x16x16f16(p0[i], v1, O01, 0, 0, 0);
            O10 = __builtin_amdgcn_mfma_f32_16x16x16f16(p1[i], v0, O10, 0, 0, 0);
            O11 = __builtin_amdgcn_mfma_f32_16x16x16f16(p1[i], v1, O11, 0, 0, 0);
        }
        __syncthreads();   // next-tile stage complete + all waves done reading cur
    }

    // complete row sums
    la += __shfl_xor(la, 16); la += __shfl_xor(la, 32);
    lb += __shfl_xor(lb, 16); lb += __shfl_xor(lb, 32);
    la -= 60.0f; lb -= 60.0f;               // 60 pad keys per branch contribute p=1
    float ia = 1.0f / la;
    float ib = 1.0f / lb;

    // normalize + store: O rows are quad*4+r; row j's 1/l lives in lanes with (lane&15)==j
    int kbase = br * 64 + h2 * 32;
    #pragma unroll
    for (int r = 0; r < 4; ++r) {
        int row = quad * 4 + r;
        int src = (lane & 48) | row;
        float fa = __shfl(ia, src);
        float fb = __shfl(ib, src);
        int n = n0 + row;
        if (n < NTOT) {
            int m = b * NTOT + n;
            XP[af_idx(m, kbase + q16, 4)] = (_Float16)(O00[r] * fa);
            XP[af_idx(m, kbase + 16 + q16, 4)] = (_Float16)(O01[r] * fa);
        }
        int n2 = n + 16;
        if (n2 < NTOT) {
            int m = b * NTOT + n2;
            XP[af_idx(m, kbase + q16, 4)] = (_Float16)(O10[r] * fb);
            XP[af_idx(m, kbase + 16 + q16, 4)] = (_Float16)(O11[r] * fb);
        }
    }
}

// ---------------- final projection: XP (already normalized fp16) + residual ----------------
__global__ __launch_bounds__(256) void proj_gemm(
    const _Float16* __restrict__ XP,
    const _Float16* __restrict__ Wf, const float* __restrict__ bias,
    float* __restrict__ out_f32, const float* __restrict__ x, const float* __restrict__ msg) {
    int lane = threadIdx.x & 63, wave = threadIdx.x >> 6;
    int mt = blockIdx.x * 4 + wave;
    const half8v* Ap = (const half8v*)XP + (size_t)mt * 4 * 64 + lane;
    const half8v* Bp = (const half8v*)Wf + lane;
    f32x4 acc[8];
    #pragma unroll
    for (int t = 0; t < 8; ++t) acc[t] = (f32x4){0.f, 0.f, 0.f, 0.f};
    #pragma unroll
    for (int kc = 0; kc < 4; ++kc) {
        half8v a = Ap[(size_t)kc * 64];
        #pragma unroll
        for (int t = 0; t < 8; ++t)
            acc[t] = __builtin_amdgcn_mfma_f32_16x16x32_f16(a, Bp[(size_t)(kc * 8 + t) * 64], acc[t], 0, 0, 0);
    }
    int quad = lane >> 4, n15 = lane & 15;
    #pragma unroll
    for (int r = 0; r < 4; ++r) {
        int m = mt * 16 + quad * 4 + r;
        if (m >= BB * NTOT) continue;
        int b = m / NTOT, tok = m - b * NTOT;
        const float* rp;
        float* dst;
        if (tok < N0) {
            rp = x + ((size_t)b * N0 + tok) * 128;
            dst = out_f32 + ((size_t)b * N0 + tok) * 128;
        } else {
            rp = msg + ((size_t)b * MSGN + (tok - N0)) * 128;
            dst = out_f32 + (size_t)BB * N0 * 128 + ((size_t)b * MSGN + (tok - N0)) * 128;
        }
        #pragma unroll
        for (int t = 0; t < 8; ++t) {
            int n = t * 16 + n15;
            dst[n] = acc[t][r] + bias[n] + rp[n];
        }
    }
}

extern "C" void kernel_launch(void* const* d_in, const int* in_sizes, int n_in,
                              void* d_out, int out_size, void* d_ws, size_t ws_size,
                              hipStream_t stream) {
    const float* x     = (const float*)d_in[0];
    const float* msg   = (const float*)d_in[1];
    const float* Wq    = (const float*)d_in[2];
    const float* bq    = (const float*)d_in[3];
    const float* sr1w  = (const float*)d_in[4];
    const float* sr1b  = (const float*)d_in[5];
    const float* ln1g  = (const float*)d_in[6];
    const float* ln1b  = (const float*)d_in[7];
    const float* sr2w  = (const float*)d_in[8];
    const float* sr2b  = (const float*)d_in[9];
    const float* ln2g  = (const float*)d_in[10];
    const float* ln2b  = (const float*)d_in[11];
    const float* kv1w  = (const float*)d_in[12];
    const float* kv1b  = (const float*)d_in[13];
    const float* kv2w  = (const float*)d_in[14];
    const float* kv2b  = (const float*)d_in[15];
    const float* lc1w  = (const float*)d_in[16];
    const float* lc1b  = (const float*)d_in[17];
    const float* lc2w  = (const float*)d_in[18];
    const float* lc2b  = (const float*)d_in[19];
    const float* projw = (const float*)d_in[20];
    const float* projb = (const float*)d_in[21];
    float* ws  = (float*)d_ws;
    float* out = (float*)d_out;

    _Float16* WfQ    = (_Float16*)(ws + OFF_WFQ);
    _Float16* WfKV1  = (_Float16*)(ws + OFF_WFKV1);
    _Float16* WfKV2  = (_Float16*)(ws + OFF_WFKV2);
    _Float16* WfPROJ = (_Float16*)(ws + OFF_WFPROJ);
    _Float16* WfSR1  = (_Float16*)(ws + OFF_WFSR1);
    _Float16* WfSR2  = (_Float16*)(ws + OFF_WFSR2);
    _Float16* Qh     = (_Float16*)(ws + OFF_QH);
    _Float16* XP     = (_Float16*)(ws + OFF_XP);
    _Float16* XK1    = (_Float16*)(ws + OFF_XK1);
    _Float16* XK2    = (_Float16*)(ws + OFF_XK2);
    float* kv1o      = ws + OFF_KV1O;
    float* kv2o      = ws + OFF_KV2O;
    _Float16* Kh1    = (_Float16*)(ws + OFF_KH1);
    _Float16* Vt1    = (_Float16*)(ws + OFF_VT1);
    _Float16* Kh2    = (_Float16*)(ws + OFF_KH2);
    _Float16* Vt2    = (_Float16*)(ws + OFF_VT2);

    // 1. weights swizzle + Q pad zero (49152 weight threads + 126976 pad threads)
    prep_weights<<<688, 256, 0, stream>>>(Wq, kv1w, kv2w, projw, sr1w, sr2w, ws, Qh);
    // 2. fused SR convs (split-K x4, LN+GELU) + q projection
    input_gemms<<<1159, 256, 0, stream>>>(x, msg, WfSR1, WfSR2,
                                          sr1b, ln1g, ln1b, sr2b, ln2g, ln2b,
                                          XK1, XK2, WfQ, bq, Qh);
    // 3. KV projections, both branches
    kv_gemm<<<161, 256, 0, stream>>>(XK1, XK2, WfKV1, WfKV2, kv1b, kv2b, kv1o, kv2o);
    // 4. V fixup + pack, both branches
    pack_kv<<<2816, 256, 0, stream>>>(kv1o, kv2o, lc1w, lc1b, lc2w, lc2b,
                                      Kh1, Vt1, Kh2, Vt2);
    // 5. flash attention: LDS-staged K/V, normalized output
    attn_mfma<<<dim3(33, 8, 4), 256, 0, stream>>>(Qh, Kh1, Vt1, Kh2, Vt2, XP);
    // 6. final projection + residual
    proj_gemm<<<513, 256, 0, stream>>>(XP, WfPROJ, projb, out, x, msg);
}

// Round 5
// 190.926 us; speedup vs baseline: 1.1842x; 1.0003x over previous
//
#include <hip/hip_runtime.h>
#include <math.h>

#define BB 8
#define CC 128
#define N0 4096
#define MSGN 4
#define NTOT 4100
#define IMG 64
#define NPAD 4224            // 132 tiles of 32 q-rows = 33 blocks x 4 waves exactly
#define LMP1 320
#define LMP2 1088

// ---------------- workspace layout (float indices) ----------------
#define OFF_WFQ    0
#define OFF_WFKV1  8192
#define OFF_WFKV2  16384
#define OFF_WFPROJ 24576
#define OFF_WFSR1  32768        // K=2048: 131072 f
#define OFF_WFSR2  163840       // K=512:  32768 f
#define OFF_QH     196608       // fp16 8*4*4224*32 = 4325376 h = 2162688 f -> end 2359296
#define OFF_XK1    2359296      // 133120 f (dead after kv_gemm)
#define OFF_XK2    2492416      // 526336 f (dead after kv_gemm)
#define OFF_KV1O   3018752      // 266240 f (dead after pack_kv)
#define OFF_KV2O   3284992      // 1052672 f (dead after pack_kv)
#define OFF_KH1    4337664      // 81920 f
#define OFF_VT1    4419584      // 81920 f  ([b,h2][key>>2][d16:16][dhalf][key&3])
#define OFF_KH2    4501504      // 278528 f
#define OFF_VT2    4780032      // 278528 f -> end 5058560
#define OFF_XP     5058560      // normalized attn O frags (fp16): 2101248 f -> end 7159808 (28.6 MB)

typedef _Float16 half8v __attribute__((ext_vector_type(8)));
typedef _Float16 half4v __attribute__((ext_vector_type(4)));
typedef float f32x4 __attribute__((ext_vector_type(4)));

__device__ __forceinline__ size_t af_idx(int m, int k, int Kc) {
    return ((size_t)((m >> 4) * Kc + (k >> 5)) * 64 + ((k >> 3) & 3) * 16 + (m & 15)) * 8 + (k & 7);
}

// exp2 (scores carry log2e folded into Q scale)
__device__ __forceinline__ float exp2_fast(float x) {
#if __has_builtin(__builtin_amdgcn_exp2f)
    return __builtin_amdgcn_exp2f(x);
#else
    return __expf(x * 0.6931471805599453f);
#endif
}

// async global->LDS, 16B per lane; LDS dest = uniform base + lane*16
__device__ __forceinline__ void gload16(const _Float16* g, _Float16* l) {
    __builtin_amdgcn_global_load_lds(
        (const __attribute__((address_space(1))) unsigned int*)g,
        (__attribute__((address_space(3))) unsigned int*)l, 16, 0, 0);
}

// ---------------- weight prep (B-frag swizzle) + Q-pad zero ----------------
__global__ void prep_weights(const float* __restrict__ Wq, const float* __restrict__ kv1,
                             const float* __restrict__ kv2, const float* __restrict__ proj,
                             const float* __restrict__ sr1w, const float* __restrict__ sr2w,
                             float* __restrict__ ws, _Float16* __restrict__ Qh) {
    int u = blockIdx.x * blockDim.x + threadIdx.x;
    if (u >= 49152) {
        int idx = u - 49152;
        if (idx >= BB * 4 * (NPAD - NTOT) * 32) return;
        int d = idx & 31;
        int rest = idx >> 5;
        int n = NTOT + rest % (NPAD - NTOT);
        int rest2 = rest / (NPAD - NTOT);
        int hg = rest2 & 3;
        int b = rest2 >> 2;
        Qh[((size_t)(b * 4 + hg) * NPAD + n) * 32 + d] = (_Float16)0.f;
        return;
    }
    int seg, base;
    const float* w = nullptr;
    _Float16* dst;
    if (u < 2048)        { seg = 0; base = u;          w = Wq;   dst = (_Float16*)(ws + OFF_WFQ); }
    else if (u < 4096)   { seg = 0; base = u - 2048;   w = kv1;  dst = (_Float16*)(ws + OFF_WFKV1); }
    else if (u < 6144)   { seg = 0; base = u - 4096;   w = kv2;  dst = (_Float16*)(ws + OFF_WFKV2); }
    else if (u < 8192)   { seg = 0; base = u - 6144;   w = proj; dst = (_Float16*)(ws + OFF_WFPROJ); }
    else if (u < 40960)  { seg = 1; base = u - 8192;   w = sr1w; dst = (_Float16*)(ws + OFF_WFSR1); }
    else                 { seg = 2; base = u - 40960;  w = sr2w; dst = (_Float16*)(ws + OFF_WFSR2); }
    int lane = base & 63;
    int t = (base >> 6) & 7;
    int kc = base >> 9;
    int n = t * 16 + (lane & 15);
    int k0 = kc * 32 + (lane >> 4) * 8;
    half8v val;
    #pragma unroll
    for (int j = 0; j < 8; ++j) {
        int k = k0 + j;
        float v;
        if (seg == 0) v = w[n * 128 + k];
        else if (seg == 1) v = w[(n * 128 + (k & 127)) * 16 + (k >> 7)];
        else v = w[(n * 128 + (k & 127)) * 4 + (k >> 7)];
        val[j] = (_Float16)v;
    }
    *(half8v*)(dst + (size_t)base * 8) = val;
}

// ---------------- SR partial gemm (fused im2col gather), K-slice per wave ----------------
template<int S, int WR, int LL, int LM, int KW>
__device__ __forceinline__ void sr_partial(
    int mtile, int kcbase, int lane, const float* __restrict__ x,
    const float* __restrict__ msg, const _Float16* __restrict__ Wf, f32x4 acc[8]) {
    int m15 = lane & 15, quadk = lane >> 4;
    int m = mtile * 16 + m15;
    bool valid = m < BB * LM;
    const float* base = x;
    bool isimg = false;
    if (valid) {
        int b = m / LM, tok = m - b * LM;
        if (tok < LL) {
            int hr = tok / WR, wr = tok - hr * WR;
            base = x + ((size_t)b * N0 + hr * S * IMG + wr * S) * 128;
            isimg = true;
        } else {
            base = msg + ((size_t)b * MSGN + (tok - LL)) * 128;
        }
    }
    const half8v* Bp = (const half8v*)Wf + lane;
    for (int kk = 0; kk < KW; ++kk) {
        int kc = kcbase + kk;
        int k0 = (kc * 4 + quadk) * 8;
        int c = k0 & 127, ij = k0 >> 7;
        half8v a;
        if (valid) {
            int off;
            if (isimg) {
                int ki = ij / S, kj = ij - ki * S;
                off = (ki * IMG + kj) * 128 + c;
            } else off = c;
            const float4* p4 = (const float4*)(base + off);
            float4 f0 = p4[0], f1 = p4[1];
            a[0] = (_Float16)f0.x; a[1] = (_Float16)f0.y; a[2] = (_Float16)f0.z; a[3] = (_Float16)f0.w;
            a[4] = (_Float16)f1.x; a[5] = (_Float16)f1.y; a[6] = (_Float16)f1.z; a[7] = (_Float16)f1.w;
        } else {
            #pragma unroll
            for (int j = 0; j < 8; ++j) a[j] = (_Float16)0.f;
        }
        #pragma unroll
        for (int t = 0; t < 8; ++t)
            acc[t] = __builtin_amdgcn_mfma_f32_16x16x32_f16(a, Bp[(size_t)(kc * 8 + t) * 64], acc[t], 0, 0, 0);
    }
}

// ---------------- fused input gemms ----------------
// [0,132)    SR1: split-K x4, LDS reduce, LN+GELU  (K=2048)
// [132,261)  SR2: full-K per wave, in-register LN+GELU (K=512, no barriers)
// [261,1286) Q projection, N-split x2 (wave = (m-tile, n-half))
__global__ __launch_bounds__(256) void input_gemms(
    const float* __restrict__ x, const float* __restrict__ msg,
    const _Float16* __restrict__ Wf1, const _Float16* __restrict__ Wf2,
    const float* __restrict__ b1, const float* __restrict__ g1, const float* __restrict__ be1,
    const float* __restrict__ b2, const float* __restrict__ g2, const float* __restrict__ be2,
    _Float16* __restrict__ XK1, _Float16* __restrict__ XK2,
    const _Float16* __restrict__ WfQ, const float* __restrict__ bq,
    _Float16* __restrict__ Qh) {
    __shared__ float red[4][2048];
    int tid = threadIdx.x;
    int lane = tid & 63, wave = tid >> 6;
    int bid = blockIdx.x;

    if (bid >= 261) {
        // ---- q projection path (direct x/msg gather, K=128), N-split x2 ----
        int u = (bid - 261) * 4 + wave;        // 0..4099
        int mt = u >> 1, nh = u & 1;
        int m15 = lane & 15, quadk = lane >> 4;
        int m = mt * 16 + m15;
        bool valid = m < BB * NTOT;
        const float* rowp = x;
        if (valid) {
            int b = m / NTOT, n = m - b * NTOT;
            rowp = (n < N0) ? (x + ((size_t)b * N0 + n) * 128)
                            : (msg + ((size_t)b * MSGN + (n - N0)) * 128);
        }
        const half8v* Bp = (const half8v*)WfQ + lane;
        f32x4 acc[4];
        #pragma unroll
        for (int t = 0; t < 4; ++t) acc[t] = (f32x4){0.f, 0.f, 0.f, 0.f};
        #pragma unroll
        for (int kc = 0; kc < 4; ++kc) {
            half8v a;
            if (valid) {
                const float4* p4 = (const float4*)(rowp + (kc * 4 + quadk) * 8);
                float4 f0 = p4[0], f1 = p4[1];
                a[0] = (_Float16)f0.x; a[1] = (_Float16)f0.y; a[2] = (_Float16)f0.z; a[3] = (_Float16)f0.w;
                a[4] = (_Float16)f1.x; a[5] = (_Float16)f1.y; a[6] = (_Float16)f1.z; a[7] = (_Float16)f1.w;
            } else {
                #pragma unroll
                for (int j = 0; j < 8; ++j) a[j] = (_Float16)0.f;
            }
            #pragma unroll
            for (int t = 0; t < 4; ++t)
                acc[t] = __builtin_amdgcn_mfma_f32_16x16x32_f16(a, Bp[(size_t)(kc * 8 + nh * 4 + t) * 64], acc[t], 0, 0, 0);
        }
        int quad = lane >> 4, n15 = lane & 15;
        // 1/sqrt(32) * log2(e): attn uses exp2 directly on the scores
        const float qscale = 0.17677669529663687f * 1.4426950408889634f;
        #pragma unroll
        for (int r = 0; r < 4; ++r) {
            int mm = mt * 16 + quad * 4 + r;
            if (mm >= BB * NTOT) continue;
            int b = mm / NTOT, tok = mm - b * NTOT;
            #pragma unroll
            for (int t = 0; t < 4; ++t) {
                int n = nh * 64 + t * 16 + n15;
                Qh[((size_t)(b * 4 + (n >> 5)) * NPAD + tok) * 32 + (n & 31)] =
                    (_Float16)((acc[t][r] + bq[n]) * qscale);
            }
        }
        return;
    }

    if (bid >= 132) {
        // ---- SR2 path: full K=512 per wave, in-register LN+GELU, no barriers ----
        int mtile = (bid - 132) * 4 + wave;    // 0..515 (514 real)
        f32x4 acc[8];
        #pragma unroll
        for (int t = 0; t < 8; ++t) acc[t] = (f32x4){0.f, 0.f, 0.f, 0.f};
        sr_partial<2, 32, 1024, 1028, 16>(mtile, 0, lane, x, msg, Wf2, acc);
        int quad = lane >> 4, n15 = lane & 15;
        float bb[8], gg[8], eb[8];
        #pragma unroll
        for (int j = 0; j < 8; ++j) {
            bb[j] = b2[j * 16 + n15];
            gg[j] = g2[j * 16 + n15];
            eb[j] = be2[j * 16 + n15];
        }
        #pragma unroll
        for (int r = 0; r < 4; ++r) {
            int m = mtile * 16 + quad * 4 + r;
            float s = 0.f;
            #pragma unroll
            for (int j = 0; j < 8; ++j) s += acc[j][r] + bb[j];
            #pragma unroll
            for (int off = 1; off < 16; off <<= 1) s += __shfl_xor(s, off);
            float mu = s * (1.f / 128.f);
            float q = 0.f;
            #pragma unroll
            for (int j = 0; j < 8; ++j) { float d = acc[j][r] + bb[j] - mu; q += d * d; }
            #pragma unroll
            for (int off = 1; off < 16; off <<= 1) q += __shfl_xor(q, off);
            float rs = rsqrtf(q * (1.f / 128.f) + 1e-5f);
            if (m < 8224) {
                #pragma unroll
                for (int j = 0; j < 8; ++j) {
                    float y = (acc[j][r] + bb[j] - mu) * rs * gg[j] + eb[j];
                    y = 0.5f * y * (1.f + erff(y * 0.70710678118654752f));
                    XK2[af_idx(m, j * 16 + n15, 4)] = (_Float16)y;
                }
            }
        }
        return;
    }

    // ---- SR1 path: split-K x4 per m-tile, LDS reduce, LN+GELU ----
    f32x4 acc[8];
    #pragma unroll
    for (int t = 0; t < 8; ++t) acc[t] = (f32x4){0.f, 0.f, 0.f, 0.f};
    int mtile = bid;
    sr_partial<4, 16, 256, 260, 16>(mtile, wave * 16, lane, x, msg, Wf1, acc);
    int quad = lane >> 4, n15 = lane & 15;
    #pragma unroll
    for (int t = 0; t < 8; ++t)
        #pragma unroll
        for (int r = 0; r < 4; ++r)
            red[wave][(quad * 4 + r) * 128 + t * 16 + n15] = acc[t][r];
    __syncthreads();
    for (int e = tid; e < 2048; e += 256)
        red[0][e] = red[0][e] + red[1][e] + red[2][e] + red[3][e];
    __syncthreads();
    int r16 = tid >> 4, l16 = tid & 15;
    int m = mtile * 16 + r16;
    float v[8];
    float s = 0.f;
    #pragma unroll
    for (int j = 0; j < 8; ++j) { v[j] = red[0][r16 * 128 + j * 16 + l16] + b1[j * 16 + l16]; s += v[j]; }
    #pragma unroll
    for (int off = 1; off < 16; off <<= 1) s += __shfl_xor(s, off);
    float mu = s * (1.f / 128.f);
    float q = 0.f;
    #pragma unroll
    for (int j = 0; j < 8; ++j) { v[j] -= mu; q += v[j] * v[j]; }
    #pragma unroll
    for (int off = 1; off < 16; off <<= 1) q += __shfl_xor(q, off);
    float rs = rsqrtf(q * (1.f / 128.f) + 1e-5f);
    if (m < 2080) {
        #pragma unroll
        for (int j = 0; j < 8; ++j) {
            int n = j * 16 + l16;
            float y = v[j] * rs * g1[n] + be1[n];
            y = 0.5f * y * (1.f + erff(y * 0.70710678118654752f));
            XK1[af_idx(m, n, 4)] = (_Float16)y;
        }
    }
}

// ---------------- merged KV gemm (both branches), N-split x2 ----------------
__global__ __launch_bounds__(256) void kv_gemm(
    const _Float16* __restrict__ XK1, const _Float16* __restrict__ XK2,
    const _Float16* __restrict__ Wf1, const _Float16* __restrict__ Wf2,
    const float* __restrict__ b1, const float* __restrict__ b2,
    float* __restrict__ o1, float* __restrict__ o2) {
    int lane = threadIdx.x & 63, wave = threadIdx.x >> 6;
    int u = blockIdx.x * 4 + wave;      // 0..1287
    int t = u >> 1, nh = u & 1;
    int lt;
    const half8v* Ap;
    const half8v* Bp;
    const float* bias;
    float* outp;
    if (t < 130) { lt = t;       Ap = (const half8v*)XK1 + (size_t)lt * 4 * 64 + lane; Bp = (const half8v*)Wf1 + lane; bias = b1; outp = o1; }
    else         { lt = t - 130; Ap = (const half8v*)XK2 + (size_t)lt * 4 * 64 + lane; Bp = (const half8v*)Wf2 + lane; bias = b2; outp = o2; }
    f32x4 acc[4];
    #pragma unroll
    for (int tt = 0; tt < 4; ++tt) acc[tt] = (f32x4){0.f, 0.f, 0.f, 0.f};
    #pragma unroll
    for (int kc = 0; kc < 4; ++kc) {
        half8v a = Ap[(size_t)kc * 64];
        #pragma unroll
        for (int tt = 0; tt < 4; ++tt)
            acc[tt] = __builtin_amdgcn_mfma_f32_16x16x32_f16(a, Bp[(size_t)(kc * 8 + nh * 4 + tt) * 64], acc[tt], 0, 0, 0);
    }
    int quad = lane >> 4, n15 = lane & 15;
    #pragma unroll
    for (int r = 0; r < 4; ++r) {
        int m = lt * 16 + quad * 4 + r;
        #pragma unroll
        for (int tt = 0; tt < 4; ++tt) {
            int n = nh * 64 + tt * 16 + n15;
            outp[(size_t)m * 128 + n] = acc[tt][r] + bias[n];
        }
    }
}

// ---------------- merged V-fixup + fp16 pack (both branches) ----------------
// Vt layout: [b,h2][key>>2][d16:16][dhalf:2][key&3] so a lane's PV B-frag
// (both d-halves) is one contiguous 16B load.
__global__ void pack_kv(const float* __restrict__ kv1o, const float* __restrict__ kv2o,
                        const float* __restrict__ lc1w, const float* __restrict__ lc1b,
                        const float* __restrict__ lc2w, const float* __restrict__ lc2b,
                        _Float16* __restrict__ Kh1, _Float16* __restrict__ Vt1,
                        _Float16* __restrict__ Kh2, _Float16* __restrict__ Vt2) {
    int idx = blockIdx.x * 256 + threadIdx.x;
    const int T1 = BB * LMP1 * 64;
    const float* kv;
    const float* lcw;
    const float* lcb;
    _Float16* Kh;
    _Float16* Vt;
    int Wr, L, Lm, Lmp, li;
    if (idx < T1) { li = idx;      kv = kv1o; lcw = lc1w; lcb = lc1b; Kh = Kh1; Vt = Vt1; Wr = 16; L = 256;  Lm = 260;  Lmp = LMP1; }
    else          { li = idx - T1; kv = kv2o; lcw = lc2w; lcb = lc2b; Kh = Kh2; Vt = Vt2; Wr = 32; L = 1024; Lm = 1028; Lmp = LMP2; }
    int ch = li & 63;
    int rest = li >> 6;
    int n = rest % Lmp;
    int b = rest / Lmp;
    int h2 = ch >> 5, d = ch & 31;
    int Hr = L / Wr;
    float kval = 0.f, vnew = 0.f;
    if (n < Lm) {
        const float* kvb = kv + (size_t)b * Lm * 128;
        kval = kvb[(size_t)n * 128 + ch];
        float v = kvb[(size_t)n * 128 + 64 + ch];
        float add;
        if (n < L) {
            int hr = n / Wr, wr = n - hr * Wr;
            float sum = lcb[ch];
            #pragma unroll
            for (int ki = 0; ki < 3; ++ki)
                #pragma unroll
                for (int kj = 0; kj < 3; ++kj) {
                    int y = hr + ki - 1, xx = wr + kj - 1;
                    if ((unsigned)y < (unsigned)Hr && (unsigned)xx < (unsigned)Wr)
                        sum += lcw[ch * 9 + ki * 3 + kj] * kvb[((size_t)y * Wr + xx) * 128 + 64 + ch];
                }
            add = sum;
        } else {
            add = v;   // msg tokens: v_add = v => v_new = 2v
        }
        vnew = v + add;
    }
    Kh[((size_t)(b * 2 + h2) * Lmp + n) * 32 + d] = (_Float16)kval;
    Vt[(size_t)(b * 2 + h2) * Lmp * 32 + (size_t)(n >> 2) * 128
       + (d & 15) * 8 + ((d >> 4) << 2) + (n & 3)] = (_Float16)vnew;
}

// ---------------- flash attention: LDS-staged K/V shared by 4 waves ----------------
// Block: 4 waves = 4 q-tiles of 32 rows, same (b, h2, br). K/V 64-key tiles staged
// cooperatively into double-buffered LDS via global_load_lds (K fragment-permuted
// on the GLOBAL source side; LDS dest linear -> conflict-free ds_read_b128).
// No split-K: l complete per wave -> normalize in-register, store fp16 once.
// Pad keys (60/branch): K=0 -> p=1 -> l -= 60; V=0 so O unaffected.
__global__ __launch_bounds__(256, 4) void attn_mfma(
    const _Float16* __restrict__ Qh,
    const _Float16* __restrict__ Kh1, const _Float16* __restrict__ Vt1,
    const _Float16* __restrict__ Kh2, const _Float16* __restrict__ Vt2,
    _Float16* __restrict__ XP) {
    __shared__ _Float16 sK[2][2048];
    __shared__ _Float16 sV[2][2048];
    int tid = threadIdx.x;
    int lane = tid & 63, wave = tid >> 6;
    int b = blockIdx.y;
    int z = blockIdx.z;
    int h2 = z & 1, br = 1 - (z >> 1);     // long blocks (br=1) dispatch first
    int tile = blockIdx.x * 4 + wave;      // 0..131, all valid (NPAD=4224)
    int n0 = tile * 32;
    int q16 = lane & 15, quad = lane >> 4;
    const f32x4 zf = {0.f, 0.f, 0.f, 0.f};
    int NT = br ? (LMP2 / 64) : (LMP1 / 64);
    int Lmp = br ? LMP2 : LMP1;
    const _Float16* kb = (br ? Kh2 : Kh1) + (size_t)(b * 2 + h2) * Lmp * 32;
    const _Float16* vb = (br ? Vt2 : Vt1) + (size_t)(b * 2 + h2) * Lmp * 32;
    int hg = br * 2 + h2;
    const _Float16* qp = Qh + ((size_t)(b * 4 + hg) * NPAD + n0 + q16) * 32 + quad * 8;
    half8v qf0 = *(const half8v*)qp;
    half8v qf1 = *(const half8v*)(qp + 512);   // +16 rows
    f32x4 O00 = zf, O01 = zf, O10 = zf, O11 = zf;
    float la = 0.f, lb = 0.f;

    // per-lane staging source offsets within a 64-key tile (2048 halfs).
    // K: LDS slot j holds K[key = (j&15) + 16*subtile][d = (j>>4)*8..+7] -> permuted source.
    // V: tile is already fragment-linear in Vt -> linear source.
    int ksrc = (wave * 16 + q16) * 32 + quad * 8;
    int vsrc = wave * 512 + lane * 8;

    gload16(kb + ksrc, &sK[0][wave * 512]);
    gload16(vb + vsrc, &sV[0][wave * 512]);
    __syncthreads();                            // drains vmcnt before barrier

    for (int t = 0; t < NT; ++t) {
        int cur = t & 1;
        if (t + 1 < NT) {                       // stage next tile (async, overlaps compute)
            size_t o = (size_t)(t + 1) * 2048;
            gload16(kb + o + ksrc, &sK[cur ^ 1][wave * 512]);
            gload16(vb + o + vsrc, &sV[cur ^ 1][wave * 512]);
        }
        half8v kf[4], vv[4];
        #pragma unroll
        for (int i = 0; i < 4; ++i)
            kf[i] = *(const half8v*)&sK[cur][i * 512 + lane * 8];
        #pragma unroll
        for (int i = 0; i < 4; ++i)
            vv[i] = *(const half8v*)&sV[cur][i * 512 + quad * 128 + q16 * 8];

        // S = K·Q^T for both q-tiles, exp2 -> p (scores already log2-scaled)
        half4v p0[4], p1[4];
        #pragma unroll
        for (int i = 0; i < 4; ++i) {
            f32x4 s0 = __builtin_amdgcn_mfma_f32_16x16x32_f16(kf[i], qf0, zf, 0, 0, 0);
            f32x4 s1 = __builtin_amdgcn_mfma_f32_16x16x32_f16(kf[i], qf1, zf, 0, 0, 0);
            half4v a, c;
            #pragma unroll
            for (int r = 0; r < 4; ++r) {
                float e0 = exp2_fast(s0[r]); la += e0; a[r] = (_Float16)e0;
                float e1 = exp2_fast(s1[r]); lb += e1; c[r] = (_Float16)e1;
            }
            p0[i] = a; p1[i] = c;
        }
        // PV for both q-tiles
        #pragma unroll
        for (int i = 0; i < 4; ++i) {
            half4v v0 = __builtin_shufflevector(vv[i], vv[i], 0, 1, 2, 3);
            half4v v1 = __builtin_shufflevector(vv[i], vv[i], 4, 5, 6, 7);
            O00 = __builtin_amdgcn_mfma_f32_16x16x16f16(p0[i], v0, O00, 0, 0, 0);
            O01 = __builtin_amdgcn_mfma_f32_16x16x16f16(p0[i], v1, O01, 0, 0, 0);
            O10 = __builtin_amdgcn_mfma_f32_16x16x16f16(p1[i], v0, O10, 0, 0, 0);
            O11 = __builtin_amdgcn_mfma_f32_16x16x16f16(p1[i], v1, O11, 0, 0, 0);
        }
        __syncthreads();   // next-tile stage complete + all waves done reading cur
    }

    // complete row sums
    la += __shfl_xor(la, 16); la += __shfl_xor(la, 32);
    lb += __shfl_xor(lb, 16); lb += __shfl_xor(lb, 32);
    la -= 60.0f; lb -= 60.0f;               // 60 pad keys per branch contribute p=1
    float ia = 1.0f / la;
    float ib = 1.0f / lb;

    // normalize + store: O rows are quad*4+r; row j's 1/l lives in lanes with (lane&15)==j
    int kbase = br * 64 + h2 * 32;
    #pragma unroll
    for (int r = 0; r < 4; ++r) {
        int row = quad * 4 + r;
        int src = (lane & 48) | row;
        float fa = __shfl(ia, src);
        float fb = __shfl(ib, src);
        int n = n0 + row;
        if (n < NTOT) {
            int m = b * NTOT + n;
            XP[af_idx(m, kbase + q16, 4)] = (_Float16)(O00[r] * fa);
            XP[af_idx(m, kbase + 16 + q16, 4)] = (_Float16)(O01[r] * fa);
        }
        int n2 = n + 16;
        if (n2 < NTOT) {
            int m = b * NTOT + n2;
            XP[af_idx(m, kbase + q16, 4)] = (_Float16)(O10[r] * fb);
            XP[af_idx(m, kbase + 16 + q16, 4)] = (_Float16)(O11[r] * fb);
        }
    }
}

// ---------------- final projection: XP (normalized fp16) + residual, N-split x2 ----------------
__global__ __launch_bounds__(256) void proj_gemm(
    const _Float16* __restrict__ XP,
    const _Float16* __restrict__ Wf, const float* __restrict__ bias,
    float* __restrict__ out_f32, const float* __restrict__ x, const float* __restrict__ msg) {
    int lane = threadIdx.x & 63, wave = threadIdx.x >> 6;
    int u = blockIdx.x * 4 + wave;      // 0..4099
    int mt = u >> 1, nh = u & 1;
    const half8v* Ap = (const half8v*)XP + (size_t)mt * 4 * 64 + lane;
    const half8v* Bp = (const half8v*)Wf + lane;
    f32x4 acc[4];
    #pragma unroll
    for (int t = 0; t < 4; ++t) acc[t] = (f32x4){0.f, 0.f, 0.f, 0.f};
    #pragma unroll
    for (int kc = 0; kc < 4; ++kc) {
        half8v a = Ap[(size_t)kc * 64];
        #pragma unroll
        for (int t = 0; t < 4; ++t)
            acc[t] = __builtin_amdgcn_mfma_f32_16x16x32_f16(a, Bp[(size_t)(kc * 8 + nh * 4 + t) * 64], acc[t], 0, 0, 0);
    }
    int quad = lane >> 4, n15 = lane & 15;
    #pragma unroll
    for (int r = 0; r < 4; ++r) {
        int m = mt * 16 + quad * 4 + r;
        if (m >= BB * NTOT) continue;
        int b = m / NTOT, tok = m - b * NTOT;
        const float* rp;
        float* dst;
        if (tok < N0) {
            rp = x + ((size_t)b * N0 + tok) * 128;
            dst = out_f32 + ((size_t)b * N0 + tok) * 128;
        } else {
            rp = msg + ((size_t)b * MSGN + (tok - N0)) * 128;
            dst = out_f32 + (size_t)BB * N0 * 128 + ((size_t)b * MSGN + (tok - N0)) * 128;
        }
        #pragma unroll
        for (int t = 0; t < 4; ++t) {
            int n = nh * 64 + t * 16 + n15;
            dst[n] = acc[t][r] + bias[n] + rp[n];
        }
    }
}

extern "C" void kernel_launch(void* const* d_in, const int* in_sizes, int n_in,
                              void* d_out, int out_size, void* d_ws, size_t ws_size,
                              hipStream_t stream) {
    const float* x     = (const float*)d_in[0];
    const float* msg   = (const float*)d_in[1];
    const float* Wq    = (const float*)d_in[2];
    const float* bq    = (const float*)d_in[3];
    const float* sr1w  = (const float*)d_in[4];
    const float* sr1b  = (const float*)d_in[5];
    const float* ln1g  = (const float*)d_in[6];
    const float* ln1b  = (const float*)d_in[7];
    const float* sr2w  = (const float*)d_in[8];
    const float* sr2b  = (const float*)d_in[9];
    const float* ln2g  = (const float*)d_in[10];
    const float* ln2b  = (const float*)d_in[11];
    const float* kv1w  = (const float*)d_in[12];
    const float* kv1b  = (const float*)d_in[13];
    const float* kv2w  = (const float*)d_in[14];
    const float* kv2b  = (const float*)d_in[15];
    const float* lc1w  = (const float*)d_in[16];
    const float* lc1b  = (const float*)d_in[17];
    const float* lc2w  = (const float*)d_in[18];
    const float* lc2b  = (const float*)d_in[19];
    const float* projw = (const float*)d_in[20];
    const float* projb = (const float*)d_in[21];
    float* ws  = (float*)d_ws;
    float* out = (float*)d_out;

    _Float16* WfQ    = (_Float16*)(ws + OFF_WFQ);
    _Float16* WfKV1  = (_Float16*)(ws + OFF_WFKV1);
    _Float16* WfKV2  = (_Float16*)(ws + OFF_WFKV2);
    _Float16* WfPROJ = (_Float16*)(ws + OFF_WFPROJ);
    _Float16* WfSR1  = (_Float16*)(ws + OFF_WFSR1);
    _Float16* WfSR2  = (_Float16*)(ws + OFF_WFSR2);
    _Float16* Qh     = (_Float16*)(ws + OFF_QH);
    _Float16* XP     = (_Float16*)(ws + OFF_XP);
    _Float16* XK1    = (_Float16*)(ws + OFF_XK1);
    _Float16* XK2    = (_Float16*)(ws + OFF_XK2);
    float* kv1o      = ws + OFF_KV1O;
    float* kv2o      = ws + OFF_KV2O;
    _Float16* Kh1    = (_Float16*)(ws + OFF_KH1);
    _Float16* Vt1    = (_Float16*)(ws + OFF_VT1);
    _Float16* Kh2    = (_Float16*)(ws + OFF_KH2);
    _Float16* Vt2    = (_Float16*)(ws + OFF_VT2);

    // 1. weights swizzle + Q pad zero
    prep_weights<<<688, 256, 0, stream>>>(Wq, kv1w, kv2w, projw, sr1w, sr2w, ws, Qh);
    // 2. fused SR convs + q projection (SR1 split-K / SR2 full-K in-reg LN / Q N-split)
    input_gemms<<<1286, 256, 0, stream>>>(x, msg, WfSR1, WfSR2,
                                          sr1b, ln1g, ln1b, sr2b, ln2g, ln2b,
                                          XK1, XK2, WfQ, bq, Qh);
    // 3. KV projections, both branches, N-split x2
    kv_gemm<<<322, 256, 0, stream>>>(XK1, XK2, WfKV1, WfKV2, kv1b, kv2b, kv1o, kv2o);
    // 4. V fixup + pack, both branches
    pack_kv<<<2816, 256, 0, stream>>>(kv1o, kv2o, lc1w, lc1b, lc2w, lc2b,
                                      Kh1, Vt1, Kh2, Vt2);
    // 5. flash attention: LDS-staged K/V, normalized output
    attn_mfma<<<dim3(33, 8, 4), 256, 0, stream>>>(Qh, Kh1, Vt1, Kh2, Vt2, XP);
    // 6. final projection + residual, N-split x2
    proj_gemm<<<1025, 256, 0, stream>>>(XP, WfPROJ, projb, out, x, msg);
}

// Round 6
// 186.454 us; speedup vs baseline: 1.2126x; 1.0240x over previous
//
#include <hip/hip_runtime.h>
#include <math.h>

#define BB 8
#define CC 128
#define N0 4096
#define MSGN 4
#define NTOT 4100
#define IMG 64
#define NPAD 4224            // 132 tiles of 32 q-rows = 33 blocks x 4 waves exactly
#define LMP1 320
#define LMP2 1088

// ---------------- workspace layout (float indices) ----------------
#define OFF_WFQ    0
#define OFF_WFKV1  8192
#define OFF_WFKV2  16384
#define OFF_WFPROJ 24576
#define OFF_WFSR1  32768        // K=2048: 131072 f
#define OFF_WFSR2  163840       // K=512:  32768 f
#define OFF_QH     196608       // fp16 8*4*4224*32 = 2162688 f -> end 2359296
#define OFF_XK1    2359296      // (unused after kv fusion)
#define OFF_XK2    2492416      // (unused after kv fusion)
#define OFF_KV1O   3018752      // V-half only now: 8*260*64 = 133120 f
#define OFF_KV2O   3284992      // V-half only now: 8*1028*64 = 526336 f
#define OFF_KH1    4337664      // 81920 f
#define OFF_VT1    4419584      // 81920 f  ([b,h2][key>>2][d16:16][dhalf][key&3])
#define OFF_KH2    4501504      // 278528 f
#define OFF_VT2    4780032      // 278528 f -> end 5058560
#define OFF_XP     5058560      // normalized attn O frags (fp16): 2101248 f -> end 7159808 (28.6 MB)

typedef _Float16 half8v __attribute__((ext_vector_type(8)));
typedef _Float16 half4v __attribute__((ext_vector_type(4)));
typedef float f32x4 __attribute__((ext_vector_type(4)));

__device__ __forceinline__ size_t af_idx(int m, int k, int Kc) {
    return ((size_t)((m >> 4) * Kc + (k >> 5)) * 64 + ((k >> 3) & 3) * 16 + (m & 15)) * 8 + (k & 7);
}

// exp2 (scores carry log2e folded into Q scale)
__device__ __forceinline__ float exp2_fast(float x) {
#if __has_builtin(__builtin_amdgcn_exp2f)
    return __builtin_amdgcn_exp2f(x);
#else
    return __expf(x * 0.6931471805599453f);
#endif
}

// async global->LDS, 16B per lane; LDS dest = uniform base + lane*16
__device__ __forceinline__ void gload16(const _Float16* g, _Float16* l) {
    __builtin_amdgcn_global_load_lds(
        (const __attribute__((address_space(1))) unsigned int*)g,
        (__attribute__((address_space(3))) unsigned int*)l, 16, 0, 0);
}

// ---------------- weight prep (B-frag swizzle) + Q-pad zero + Kh-pad zero ----------------
// u < 49152: weight swizzle; [49152,176128): Qh pad rows; [176128,237568): Kh pad rows.
__global__ void prep_weights(const float* __restrict__ Wq, const float* __restrict__ kv1,
                             const float* __restrict__ kv2, const float* __restrict__ proj,
                             const float* __restrict__ sr1w, const float* __restrict__ sr2w,
                             float* __restrict__ ws, _Float16* __restrict__ Qh,
                             _Float16* __restrict__ Kh1, _Float16* __restrict__ Kh2) {
    int u = blockIdx.x * blockDim.x + threadIdx.x;
    if (u >= 176128) {
        // Kh pad rows (60 per stream): K=0 -> p=1, accounted by l -= 60 in attn
        int e = u - 176128;              // 0..61439 (grid exact)
        int d = e & 31;
        int rest = e >> 5;               // 0..1919
        if (rest < 960) {
            int n = 260 + rest % 60;
            int bh = rest / 60;          // b*2+h2
            Kh1[((size_t)bh * LMP1 + n) * 32 + d] = (_Float16)0.f;
        } else {
            rest -= 960;
            int n = 1028 + rest % 60;
            int bh = rest / 60;
            Kh2[((size_t)bh * LMP2 + n) * 32 + d] = (_Float16)0.f;
        }
        return;
    }
    if (u >= 49152) {
        int idx = u - 49152;             // 0..126975 (exact)
        int d = idx & 31;
        int rest = idx >> 5;
        int n = NTOT + rest % (NPAD - NTOT);
        int rest2 = rest / (NPAD - NTOT);
        int hg = rest2 & 3;
        int b = rest2 >> 2;
        Qh[((size_t)(b * 4 + hg) * NPAD + n) * 32 + d] = (_Float16)0.f;
        return;
    }
    int seg, base;
    const float* w = nullptr;
    _Float16* dst;
    if (u < 2048)        { seg = 0; base = u;          w = Wq;   dst = (_Float16*)(ws + OFF_WFQ); }
    else if (u < 4096)   { seg = 0; base = u - 2048;   w = kv1;  dst = (_Float16*)(ws + OFF_WFKV1); }
    else if (u < 6144)   { seg = 0; base = u - 4096;   w = kv2;  dst = (_Float16*)(ws + OFF_WFKV2); }
    else if (u < 8192)   { seg = 0; base = u - 6144;   w = proj; dst = (_Float16*)(ws + OFF_WFPROJ); }
    else if (u < 40960)  { seg = 1; base = u - 8192;   w = sr1w; dst = (_Float16*)(ws + OFF_WFSR1); }
    else                 { seg = 2; base = u - 40960;  w = sr2w; dst = (_Float16*)(ws + OFF_WFSR2); }
    int lane = base & 63;
    int t = (base >> 6) & 7;
    int kc = base >> 9;
    int n = t * 16 + (lane & 15);
    int k0 = kc * 32 + (lane >> 4) * 8;
    half8v val;
    #pragma unroll
    for (int j = 0; j < 8; ++j) {
        int k = k0 + j;
        float v;
        if (seg == 0) v = w[n * 128 + k];
        else if (seg == 1) v = w[(n * 128 + (k & 127)) * 16 + (k >> 7)];
        else v = w[(n * 128 + (k & 127)) * 4 + (k >> 7)];
        val[j] = (_Float16)v;
    }
    *(half8v*)(dst + (size_t)base * 8) = val;
}

// ---------------- SR partial gemm (fused im2col gather), K-slice per wave ----------------
template<int S, int WR, int LL, int LM, int KW>
__device__ __forceinline__ void sr_partial(
    int mtile, int kcbase, int lane, const float* __restrict__ x,
    const float* __restrict__ msg, const _Float16* __restrict__ Wf, f32x4 acc[8]) {
    int m15 = lane & 15, quadk = lane >> 4;
    int m = mtile * 16 + m15;
    bool valid = m < BB * LM;
    const float* base = x;
    bool isimg = false;
    if (valid) {
        int b = m / LM, tok = m - b * LM;
        if (tok < LL) {
            int hr = tok / WR, wr = tok - hr * WR;
            base = x + ((size_t)b * N0 + hr * S * IMG + wr * S) * 128;
            isimg = true;
        } else {
            base = msg + ((size_t)b * MSGN + (tok - LL)) * 128;
        }
    }
    const half8v* Bp = (const half8v*)Wf + lane;
    for (int kk = 0; kk < KW; ++kk) {
        int kc = kcbase + kk;
        int k0 = (kc * 4 + quadk) * 8;
        int c = k0 & 127, ij = k0 >> 7;
        half8v a;
        if (valid) {
            int off;
            if (isimg) {
                int ki = ij / S, kj = ij - ki * S;
                off = (ki * IMG + kj) * 128 + c;
            } else off = c;
            const float4* p4 = (const float4*)(base + off);
            float4 f0 = p4[0], f1 = p4[1];
            a[0] = (_Float16)f0.x; a[1] = (_Float16)f0.y; a[2] = (_Float16)f0.z; a[3] = (_Float16)f0.w;
            a[4] = (_Float16)f1.x; a[5] = (_Float16)f1.y; a[6] = (_Float16)f1.z; a[7] = (_Float16)f1.w;
        } else {
            #pragma unroll
            for (int j = 0; j < 8; ++j) a[j] = (_Float16)0.f;
        }
        #pragma unroll
        for (int t = 0; t < 8; ++t)
            acc[t] = __builtin_amdgcn_mfma_f32_16x16x32_f16(a, Bp[(size_t)(kc * 8 + t) * 64], acc[t], 0, 0, 0);
    }
}

// ---------------- fused input gemms + KV projection ----------------
// [0,132)    SR1: split-K x4, LDS reduce, LN+GELU, then fused KV gemm (XK stays in LDS)
// [132,261)  SR2: full-K per wave, in-register LN+GELU, per-wave fused KV gemm
// [261,1286) Q projection, N-split x2
// K-halves written directly to Kh (fp16 final layout); V-halves to vo (fp32, 64-wide).
__global__ __launch_bounds__(256) void input_gemms(
    const float* __restrict__ x, const float* __restrict__ msg,
    const _Float16* __restrict__ Wf1, const _Float16* __restrict__ Wf2,
    const float* __restrict__ b1, const float* __restrict__ g1, const float* __restrict__ be1,
    const float* __restrict__ b2, const float* __restrict__ g2, const float* __restrict__ be2,
    const _Float16* __restrict__ WfKV1, const _Float16* __restrict__ WfKV2,
    const float* __restrict__ kvb1, const float* __restrict__ kvb2,
    _Float16* __restrict__ Kh1, float* __restrict__ vo1,
    _Float16* __restrict__ Kh2, float* __restrict__ vo2,
    const _Float16* __restrict__ WfQ, const float* __restrict__ bq,
    _Float16* __restrict__ Qh) {
    __shared__ float red[4][2048];
    int tid = threadIdx.x;
    int lane = tid & 63, wave = tid >> 6;
    int bid = blockIdx.x;
    const f32x4 zf4 = {0.f, 0.f, 0.f, 0.f};

    if (bid >= 261) {
        // ---- q projection path (direct x/msg gather, K=128), N-split x2 ----
        int u = (bid - 261) * 4 + wave;        // 0..4099
        int mt = u >> 1, nh = u & 1;
        int m15 = lane & 15, quadk = lane >> 4;
        int m = mt * 16 + m15;
        bool valid = m < BB * NTOT;
        const float* rowp = x;
        if (valid) {
            int b = m / NTOT, n = m - b * NTOT;
            rowp = (n < N0) ? (x + ((size_t)b * N0 + n) * 128)
                            : (msg + ((size_t)b * MSGN + (n - N0)) * 128);
        }
        const half8v* Bp = (const half8v*)WfQ + lane;
        f32x4 acc[4];
        #pragma unroll
        for (int t = 0; t < 4; ++t) acc[t] = zf4;
        #pragma unroll
        for (int kc = 0; kc < 4; ++kc) {
            half8v a;
            if (valid) {
                const float4* p4 = (const float4*)(rowp + (kc * 4 + quadk) * 8);
                float4 f0 = p4[0], f1 = p4[1];
                a[0] = (_Float16)f0.x; a[1] = (_Float16)f0.y; a[2] = (_Float16)f0.z; a[3] = (_Float16)f0.w;
                a[4] = (_Float16)f1.x; a[5] = (_Float16)f1.y; a[6] = (_Float16)f1.z; a[7] = (_Float16)f1.w;
            } else {
                #pragma unroll
                for (int j = 0; j < 8; ++j) a[j] = (_Float16)0.f;
            }
            #pragma unroll
            for (int t = 0; t < 4; ++t)
                acc[t] = __builtin_amdgcn_mfma_f32_16x16x32_f16(a, Bp[(size_t)(kc * 8 + nh * 4 + t) * 64], acc[t], 0, 0, 0);
        }
        int quad = lane >> 4, n15 = lane & 15;
        // 1/sqrt(32) * log2(e): attn uses exp2 directly on the scores
        const float qscale = 0.17677669529663687f * 1.4426950408889634f;
        #pragma unroll
        for (int r = 0; r < 4; ++r) {
            int mm = mt * 16 + quad * 4 + r;
            if (mm >= BB * NTOT) continue;
            int b = mm / NTOT, tok = mm - b * NTOT;
            #pragma unroll
            for (int t = 0; t < 4; ++t) {
                int n = nh * 64 + t * 16 + n15;
                Qh[((size_t)(b * 4 + (n >> 5)) * NPAD + tok) * 32 + (n & 31)] =
                    (_Float16)((acc[t][r] + bq[n]) * qscale);
            }
        }
        return;
    }

    if (bid >= 132) {
        // ---- SR2: full K=512 per wave, in-register LN+GELU, per-wave fused KV ----
        int mtile = (bid - 132) * 4 + wave;    // 0..515 (514 real)
        f32x4 acc[8];
        #pragma unroll
        for (int t = 0; t < 8; ++t) acc[t] = zf4;
        sr_partial<2, 32, 1024, 1028, 16>(mtile, 0, lane, x, msg, Wf2, acc);
        int quad = lane >> 4, n15 = lane & 15;
        float bb[8], gg[8], eb[8];
        #pragma unroll
        for (int j = 0; j < 8; ++j) {
            bb[j] = b2[j * 16 + n15];
            gg[j] = g2[j * 16 + n15];
            eb[j] = be2[j * 16 + n15];
        }
        // per-wave XK tile in LDS: 16 rows x stride 136 halfs (16B-aligned rows)
        _Float16* XKw = (_Float16*)(&red[0][0]) + wave * 2176;
        #pragma unroll
        for (int r = 0; r < 4; ++r) {
            float s = 0.f;
            #pragma unroll
            for (int j = 0; j < 8; ++j) s += acc[j][r] + bb[j];
            #pragma unroll
            for (int off = 1; off < 16; off <<= 1) s += __shfl_xor(s, off);
            float mu = s * (1.f / 128.f);
            float q = 0.f;
            #pragma unroll
            for (int j = 0; j < 8; ++j) { float d = acc[j][r] + bb[j] - mu; q += d * d; }
            #pragma unroll
            for (int off = 1; off < 16; off <<= 1) q += __shfl_xor(q, off);
            float rs = rsqrtf(q * (1.f / 128.f) + 1e-5f);
            #pragma unroll
            for (int j = 0; j < 8; ++j) {
                float y = (acc[j][r] + bb[j] - mu) * rs * gg[j] + eb[j];
                y = 0.5f * y * (1.f + erff(y * 0.70710678118654752f));
                XKw[(quad * 4 + r) * 136 + j * 16 + n15] = (_Float16)y;
            }
        }
        __syncthreads();       // within-wave RAW fence (all waves uniform path)
        // fused KV: full 16x128 output for this tile
        const half8v* Bp = (const half8v*)WfKV2 + lane;
        f32x4 ka[8];
        #pragma unroll
        for (int tt = 0; tt < 8; ++tt) ka[tt] = zf4;
        #pragma unroll
        for (int kc = 0; kc < 4; ++kc) {
            half8v a = *(const half8v*)&XKw[(lane & 15) * 136 + kc * 32 + (lane >> 4) * 8];
            #pragma unroll
            for (int tt = 0; tt < 8; ++tt)
                ka[tt] = __builtin_amdgcn_mfma_f32_16x16x32_f16(a, Bp[(size_t)(kc * 8 + tt) * 64], ka[tt], 0, 0, 0);
        }
        #pragma unroll
        for (int r = 0; r < 4; ++r) {
            int m = mtile * 16 + quad * 4 + r;
            if (m >= 8224) continue;
            int b = m / 1028, tok = m - b * 1028;
            #pragma unroll
            for (int tt = 0; tt < 8; ++tt) {
                int n = tt * 16 + n15;
                float val = ka[tt][r] + kvb2[n];
                if (tt < 4) {
                    Kh2[((size_t)(b * 2 + (n >> 5)) * LMP2 + tok) * 32 + (n & 31)] = (_Float16)val;
                } else {
                    vo2[((size_t)b * 1028 + tok) * 64 + (n - 64)] = val;
                }
            }
        }
        return;
    }

    // ---- SR1: split-K x4 per m-tile, LDS reduce, LN+GELU, block-fused KV ----
    f32x4 acc[8];
    #pragma unroll
    for (int t = 0; t < 8; ++t) acc[t] = zf4;
    int mtile = bid;
    sr_partial<4, 16, 256, 260, 16>(mtile, wave * 16, lane, x, msg, Wf1, acc);
    int quad = lane >> 4, n15 = lane & 15;
    #pragma unroll
    for (int t = 0; t < 8; ++t)
        #pragma unroll
        for (int r = 0; r < 4; ++r)
            red[wave][(quad * 4 + r) * 128 + t * 16 + n15] = acc[t][r];
    __syncthreads();
    for (int e = tid; e < 2048; e += 256)
        red[0][e] = red[0][e] + red[1][e] + red[2][e] + red[3][e];
    __syncthreads();
    int r16 = tid >> 4, l16 = tid & 15;
    int m = mtile * 16 + r16;
    float v[8];
    float s = 0.f;
    #pragma unroll
    for (int j = 0; j < 8; ++j) { v[j] = red[0][r16 * 128 + j * 16 + l16] + b1[j * 16 + l16]; s += v[j]; }
    #pragma unroll
    for (int off = 1; off < 16; off <<= 1) s += __shfl_xor(s, off);
    float mu = s * (1.f / 128.f);
    float q = 0.f;
    #pragma unroll
    for (int j = 0; j < 8; ++j) { v[j] -= mu; q += v[j] * v[j]; }
    #pragma unroll
    for (int off = 1; off < 16; off <<= 1) q += __shfl_xor(q, off);
    float rs = rsqrtf(q * (1.f / 128.f) + 1e-5f);
    // XK tile to LDS (red[1] area, disjoint from red[0] reads above)
    _Float16* XKs = (_Float16*)(&red[1][0]);     // 16 x stride-136 halfs
    if (m < 2080) {
        #pragma unroll
        for (int j = 0; j < 8; ++j) {
            float y = v[j] * rs * g1[j * 16 + l16] + be1[j * 16 + l16];
            y = 0.5f * y * (1.f + erff(y * 0.70710678118654752f));
            XKs[r16 * 136 + j * 16 + l16] = (_Float16)y;
        }
    }
    __syncthreads();
    // fused KV: wave w covers t = 2w, 2w+1 (waves 0,1 -> K cols; 2,3 -> V cols)
    {
        const half8v* Bp = (const half8v*)WfKV1 + lane;
        int t0 = wave * 2;
        f32x4 ka[2];
        ka[0] = zf4; ka[1] = zf4;
        #pragma unroll
        for (int kc = 0; kc < 4; ++kc) {
            half8v a = *(const half8v*)&XKs[(lane & 15) * 136 + kc * 32 + (lane >> 4) * 8];
            #pragma unroll
            for (int tt = 0; tt < 2; ++tt)
                ka[tt] = __builtin_amdgcn_mfma_f32_16x16x32_f16(a, Bp[(size_t)(kc * 8 + t0 + tt) * 64], ka[tt], 0, 0, 0);
        }
        #pragma unroll
        for (int r = 0; r < 4; ++r) {
            int mm = mtile * 16 + quad * 4 + r;
            if (mm >= 2080) continue;
            int b = mm / 260, tok = mm - b * 260;
            #pragma unroll
            for (int tt = 0; tt < 2; ++tt) {
                int n = (t0 + tt) * 16 + n15;
                float val = ka[tt][r] + kvb1[n];
                if (n < 64) {
                    Kh1[((size_t)(b * 2 + (n >> 5)) * LMP1 + tok) * 32 + (n & 31)] = (_Float16)val;
                } else {
                    vo1[((size_t)b * 260 + tok) * 64 + (n - 64)] = val;
                }
            }
        }
    }
}

// ---------------- V-fixup + fp16 pack (V only; K already in Kh) ----------------
// Vt layout: [b,h2][key>>2][d16:16][dhalf:2][key&3] so a lane's PV B-frag
// (both d-halves) is one contiguous 16B load.
__global__ void pack_kv(const float* __restrict__ vo1, const float* __restrict__ vo2,
                        const float* __restrict__ lc1w, const float* __restrict__ lc1b,
                        const float* __restrict__ lc2w, const float* __restrict__ lc2b,
                        _Float16* __restrict__ Vt1, _Float16* __restrict__ Vt2) {
    int idx = blockIdx.x * 256 + threadIdx.x;
    const int T1 = BB * LMP1 * 64;
    const float* vo;
    const float* lcw;
    const float* lcb;
    _Float16* Vt;
    int Wr, L, Lm, Lmp, li;
    if (idx < T1) { li = idx;      vo = vo1; lcw = lc1w; lcb = lc1b; Vt = Vt1; Wr = 16; L = 256;  Lm = 260;  Lmp = LMP1; }
    else          { li = idx - T1; vo = vo2; lcw = lc2w; lcb = lc2b; Vt = Vt2; Wr = 32; L = 1024; Lm = 1028; Lmp = LMP2; }
    int ch = li & 63;
    int rest = li >> 6;
    int n = rest % Lmp;
    int b = rest / Lmp;
    int h2 = ch >> 5, d = ch & 31;
    int Hr = L / Wr;
    float vnew = 0.f;
    if (n < Lm) {
        const float* vb2 = vo + (size_t)b * Lm * 64;
        float v = vb2[(size_t)n * 64 + ch];
        float add;
        if (n < L) {
            int hr = n / Wr, wr = n - hr * Wr;
            float sum = lcb[ch];
            #pragma unroll
            for (int ki = 0; ki < 3; ++ki)
                #pragma unroll
                for (int kj = 0; kj < 3; ++kj) {
                    int y = hr + ki - 1, xx = wr + kj - 1;
                    if ((unsigned)y < (unsigned)Hr && (unsigned)xx < (unsigned)Wr)
                        sum += lcw[ch * 9 + ki * 3 + kj] * vb2[((size_t)y * Wr + xx) * 64 + ch];
                }
            add = sum;
        } else {
            add = v;   // msg tokens: v_add = v => v_new = 2v
        }
        vnew = v + add;
    }
    Vt[(size_t)(b * 2 + h2) * Lmp * 32 + (size_t)(n >> 2) * 128
       + (d & 15) * 8 + ((d >> 4) << 2) + (n & 3)] = (_Float16)vnew;
}

// ---------------- flash attention: LDS-staged K/V shared by 4 waves ----------------
// Row-sum l computed via MFMA with B = ones (same accumulator layout as O) ->
// per-row normalization needs no cross-lane shuffles.
// Pad keys (60/branch): K=0 -> p=1 -> l -= 60; V=0 so O unaffected.
__global__ __launch_bounds__(256, 4) void attn_mfma(
    const _Float16* __restrict__ Qh,
    const _Float16* __restrict__ Kh1, const _Float16* __restrict__ Vt1,
    const _Float16* __restrict__ Kh2, const _Float16* __restrict__ Vt2,
    _Float16* __restrict__ XP) {
    __shared__ _Float16 sK[2][2048];
    __shared__ _Float16 sV[2][2048];
    int tid = threadIdx.x;
    int lane = tid & 63, wave = tid >> 6;
    int b = blockIdx.y;
    int z = blockIdx.z;
    int h2 = z & 1, br = 1 - (z >> 1);     // long blocks (br=1) dispatch first
    int tile = blockIdx.x * 4 + wave;      // 0..131, all valid (NPAD=4224)
    int n0 = tile * 32;
    int q16 = lane & 15, quad = lane >> 4;
    const f32x4 zf = {0.f, 0.f, 0.f, 0.f};
    int NT = br ? (LMP2 / 64) : (LMP1 / 64);
    int Lmp = br ? LMP2 : LMP1;
    const _Float16* kb = (br ? Kh2 : Kh1) + (size_t)(b * 2 + h2) * Lmp * 32;
    const _Float16* vb = (br ? Vt2 : Vt1) + (size_t)(b * 2 + h2) * Lmp * 32;
    int hg = br * 2 + h2;
    const _Float16* qp = Qh + ((size_t)(b * 4 + hg) * NPAD + n0 + q16) * 32 + quad * 8;
    half8v qf0 = *(const half8v*)qp;
    half8v qf1 = *(const half8v*)(qp + 512);   // +16 rows
    f32x4 O00 = zf, O01 = zf, O10 = zf, O11 = zf;
    f32x4 La = zf, Lb = zf;                    // row-sum accumulators (P @ ones)
    half4v ones4;
    #pragma unroll
    for (int r = 0; r < 4; ++r) ones4[r] = (_Float16)1.f;

    // per-lane staging source offsets within a 64-key tile (2048 halfs).
    int ksrc = (wave * 16 + q16) * 32 + quad * 8;
    int vsrc = wave * 512 + lane * 8;

    gload16(kb + ksrc, &sK[0][wave * 512]);
    gload16(vb + vsrc, &sV[0][wave * 512]);
    __syncthreads();

    for (int t = 0; t < NT; ++t) {
        int cur = t & 1;
        if (t + 1 < NT) {                       // stage next tile (async, overlaps compute)
            size_t o = (size_t)(t + 1) * 2048;
            gload16(kb + o + ksrc, &sK[cur ^ 1][wave * 512]);
            gload16(vb + o + vsrc, &sV[cur ^ 1][wave * 512]);
        }
        half8v kf[4], vv[4];
        #pragma unroll
        for (int i = 0; i < 4; ++i)
            kf[i] = *(const half8v*)&sK[cur][i * 512 + lane * 8];
        #pragma unroll
        for (int i = 0; i < 4; ++i)
            vv[i] = *(const half8v*)&sV[cur][i * 512 + quad * 128 + q16 * 8];

        // S = K·Q^T for both q-tiles, exp2 -> p (scores already log2-scaled)
        half4v p0[4], p1[4];
        #pragma unroll
        for (int i = 0; i < 4; ++i) {
            f32x4 s0 = __builtin_amdgcn_mfma_f32_16x16x32_f16(kf[i], qf0, zf, 0, 0, 0);
            f32x4 s1 = __builtin_amdgcn_mfma_f32_16x16x32_f16(kf[i], qf1, zf, 0, 0, 0);
            half4v a, c;
            #pragma unroll
            for (int r = 0; r < 4; ++r) {
                a[r] = (_Float16)exp2_fast(s0[r]);
                c[r] = (_Float16)exp2_fast(s1[r]);
            }
            p0[i] = a; p1[i] = c;
        }
        // PV + row-sum for both q-tiles
        #pragma unroll
        for (int i = 0; i < 4; ++i) {
            half4v v0 = __builtin_shufflevector(vv[i], vv[i], 0, 1, 2, 3);
            half4v v1 = __builtin_shufflevector(vv[i], vv[i], 4, 5, 6, 7);
            O00 = __builtin_amdgcn_mfma_f32_16x16x16f16(p0[i], v0, O00, 0, 0, 0);
            O01 = __builtin_amdgcn_mfma_f32_16x16x16f16(p0[i], v1, O01, 0, 0, 0);
            La  = __builtin_amdgcn_mfma_f32_16x16x16f16(p0[i], ones4, La, 0, 0, 0);
            O10 = __builtin_amdgcn_mfma_f32_16x16x16f16(p1[i], v0, O10, 0, 0, 0);
            O11 = __builtin_amdgcn_mfma_f32_16x16x16f16(p1[i], v1, O11, 0, 0, 0);
            Lb  = __builtin_amdgcn_mfma_f32_16x16x16f16(p1[i], ones4, Lb, 0, 0, 0);
        }
        __syncthreads();   // next-tile stage complete + all waves done reading cur
    }

    // normalize + store: row = quad*4+r; l for that row is La[r]/Lb[r] (all cols equal)
    int kbase = br * 64 + h2 * 32;
    #pragma unroll
    for (int r = 0; r < 4; ++r) {
        float fa = 1.0f / (La[r] - 60.0f);     // 60 pad keys contribute p=1
        float fb = 1.0f / (Lb[r] - 60.0f);
        int n = n0 + quad * 4 + r;
        if (n < NTOT) {
            int m = b * NTOT + n;
            XP[af_idx(m, kbase + q16, 4)] = (_Float16)(O00[r] * fa);
            XP[af_idx(m, kbase + 16 + q16, 4)] = (_Float16)(O01[r] * fa);
        }
        int n2 = n + 16;
        if (n2 < NTOT) {
            int m = b * NTOT + n2;
            XP[af_idx(m, kbase + q16, 4)] = (_Float16)(O10[r] * fb);
            XP[af_idx(m, kbase + 16 + q16, 4)] = (_Float16)(O11[r] * fb);
        }
    }
}

// ---------------- final projection: XP (normalized fp16) + residual, N-split x2 ----------------
__global__ __launch_bounds__(256) void proj_gemm(
    const _Float16* __restrict__ XP,
    const _Float16* __restrict__ Wf, const float* __restrict__ bias,
    float* __restrict__ out_f32, const float* __restrict__ x, const float* __restrict__ msg) {
    int lane = threadIdx.x & 63, wave = threadIdx.x >> 6;
    int u = blockIdx.x * 4 + wave;      // 0..4099
    int mt = u >> 1, nh = u & 1;
    const half8v* Ap = (const half8v*)XP + (size_t)mt * 4 * 64 + lane;
    const half8v* Bp = (const half8v*)Wf + lane;
    f32x4 acc[4];
    #pragma unroll
    for (int t = 0; t < 4; ++t) acc[t] = (f32x4){0.f, 0.f, 0.f, 0.f};
    #pragma unroll
    for (int kc = 0; kc < 4; ++kc) {
        half8v a = Ap[(size_t)kc * 64];
        #pragma unroll
        for (int t = 0; t < 4; ++t)
            acc[t] = __builtin_amdgcn_mfma_f32_16x16x32_f16(a, Bp[(size_t)(kc * 8 + nh * 4 + t) * 64], acc[t], 0, 0, 0);
    }
    int quad = lane >> 4, n15 = lane & 15;
    #pragma unroll
    for (int r = 0; r < 4; ++r) {
        int m = mt * 16 + quad * 4 + r;
        if (m >= BB * NTOT) continue;
        int b = m / NTOT, tok = m - b * NTOT;
        const float* rp;
        float* dst;
        if (tok < N0) {
            rp = x + ((size_t)b * N0 + tok) * 128;
            dst = out_f32 + ((size_t)b * N0 + tok) * 128;
        } else {
            rp = msg + ((size_t)b * MSGN + (tok - N0)) * 128;
            dst = out_f32 + (size_t)BB * N0 * 128 + ((size_t)b * MSGN + (tok - N0)) * 128;
        }
        #pragma unroll
        for (int t = 0; t < 4; ++t) {
            int n = nh * 64 + t * 16 + n15;
            dst[n] = acc[t][r] + bias[n] + rp[n];
        }
    }
}

extern "C" void kernel_launch(void* const* d_in, const int* in_sizes, int n_in,
                              void* d_out, int out_size, void* d_ws, size_t ws_size,
                              hipStream_t stream) {
    const float* x     = (const float*)d_in[0];
    const float* msg   = (const float*)d_in[1];
    const float* Wq    = (const float*)d_in[2];
    const float* bq    = (const float*)d_in[3];
    const float* sr1w  = (const float*)d_in[4];
    const float* sr1b  = (const float*)d_in[5];
    const float* ln1g  = (const float*)d_in[6];
    const float* ln1b  = (const float*)d_in[7];
    const float* sr2w  = (const float*)d_in[8];
    const float* sr2b  = (const float*)d_in[9];
    const float* ln2g  = (const float*)d_in[10];
    const float* ln2b  = (const float*)d_in[11];
    const float* kv1w  = (const float*)d_in[12];
    const float* kv1b  = (const float*)d_in[13];
    const float* kv2w  = (const float*)d_in[14];
    const float* kv2b  = (const float*)d_in[15];
    const float* lc1w  = (const float*)d_in[16];
    const float* lc1b  = (const float*)d_in[17];
    const float* lc2w  = (const float*)d_in[18];
    const float* lc2b  = (const float*)d_in[19];
    const float* projw = (const float*)d_in[20];
    const float* projb = (const float*)d_in[21];
    float* ws  = (float*)d_ws;
    float* out = (float*)d_out;

    _Float16* WfQ    = (_Float16*)(ws + OFF_WFQ);
    _Float16* WfKV1  = (_Float16*)(ws + OFF_WFKV1);
    _Float16* WfKV2  = (_Float16*)(ws + OFF_WFKV2);
    _Float16* WfPROJ = (_Float16*)(ws + OFF_WFPROJ);
    _Float16* WfSR1  = (_Float16*)(ws + OFF_WFSR1);
    _Float16* WfSR2  = (_Float16*)(ws + OFF_WFSR2);
    _Float16* Qh     = (_Float16*)(ws + OFF_QH);
    _Float16* XP     = (_Float16*)(ws + OFF_XP);
    float* vo1       = ws + OFF_KV1O;
    float* vo2       = ws + OFF_KV2O;
    _Float16* Kh1    = (_Float16*)(ws + OFF_KH1);
    _Float16* Vt1    = (_Float16*)(ws + OFF_VT1);
    _Float16* Kh2    = (_Float16*)(ws + OFF_KH2);
    _Float16* Vt2    = (_Float16*)(ws + OFF_VT2);

    // 1. weights swizzle + Q pad zero + Kh pad zero (49152 + 126976 + 61440 threads)
    prep_weights<<<928, 256, 0, stream>>>(Wq, kv1w, kv2w, projw, sr1w, sr2w, ws, Qh, Kh1, Kh2);
    // 2. fused SR convs + LN/GELU + KV projection + q projection
    input_gemms<<<1286, 256, 0, stream>>>(x, msg, WfSR1, WfSR2,
                                          sr1b, ln1g, ln1b, sr2b, ln2g, ln2b,
                                          WfKV1, WfKV2, kv1b, kv2b,
                                          Kh1, vo1, Kh2, vo2,
                                          WfQ, bq, Qh);
    // 3. V fixup + pack (K already final in Kh)
    pack_kv<<<2816, 256, 0, stream>>>(vo1, vo2, lc1w, lc1b, lc2w, lc2b, Vt1, Vt2);
    // 4. flash attention: LDS-staged K/V, MFMA row-sums, normalized output
    attn_mfma<<<dim3(33, 8, 4), 256, 0, stream>>>(Qh, Kh1, Vt1, Kh2, Vt2, XP);
    // 5. final projection + residual, N-split x2
    proj_gemm<<<1025, 256, 0, stream>>>(XP, WfPROJ, projb, out, x, msg);
}

// Round 7
// 185.973 us; speedup vs baseline: 1.2158x; 1.0026x over previous
//
#include <hip/hip_runtime.h>
#include <math.h>

#define BB 8
#define CC 128
#define N0 4096
#define MSGN 4
#define NTOT 4100
#define IMG 64
#define NPAD 4224            // 132 tiles of 32 q-rows = 33 blocks x 4 waves exactly
#define LMP1 320
#define LMP2 1088

// ---------------- workspace layout (float indices) ----------------
#define OFF_WFQ    0
#define OFF_WFKV1  8192
#define OFF_WFKV2  16384
#define OFF_WFPROJ 24576
#define OFF_WFSR1  32768        // K=2048: 131072 f
#define OFF_WFSR2  163840       // K=512:  32768 f
#define OFF_QH     196608       // fp16 8*4*4224*32 = 2162688 f -> end 2359296
#define OFF_XK1    2359296      // (unused after kv fusion)
#define OFF_XK2    2492416      // (unused after kv fusion)
#define OFF_KV1O   3018752      // V-half only now: 8*260*64 = 133120 f
#define OFF_KV2O   3284992      // V-half only now: 8*1028*64 = 526336 f
#define OFF_KH1    4337664      // 81920 f
#define OFF_VT1    4419584      // 81920 f  ([b,h2][key>>2][d16:16][dhalf][key&3])
#define OFF_KH2    4501504      // 278528 f
#define OFF_VT2    4780032      // 278528 f -> end 5058560
#define OFF_XP     5058560      // normalized attn O frags (fp16): 2101248 f -> end 7159808 (28.6 MB)

typedef _Float16 half8v __attribute__((ext_vector_type(8)));
typedef _Float16 half4v __attribute__((ext_vector_type(4)));
typedef float f32x4 __attribute__((ext_vector_type(4)));

__device__ __forceinline__ size_t af_idx(int m, int k, int Kc) {
    return ((size_t)((m >> 4) * Kc + (k >> 5)) * 64 + ((k >> 3) & 3) * 16 + (m & 15)) * 8 + (k & 7);
}

// exp2 (scores carry log2e folded into Q scale)
__device__ __forceinline__ float exp2_fast(float x) {
#if __has_builtin(__builtin_amdgcn_exp2f)
    return __builtin_amdgcn_exp2f(x);
#else
    return __expf(x * 0.6931471805599453f);
#endif
}

// async global->LDS, 16B per lane; LDS dest = uniform base + lane*16
__device__ __forceinline__ void gload16(const _Float16* g, _Float16* l) {
    __builtin_amdgcn_global_load_lds(
        (const __attribute__((address_space(1))) unsigned int*)g,
        (__attribute__((address_space(3))) unsigned int*)l, 16, 0, 0);
}

// ---------------- weight prep (B-frag swizzle) + Q-pad zero + Kh-pad zero ----------------
// u < 49152: weight swizzle; [49152,176128): Qh pad rows; [176128,237568): Kh pad rows.
__global__ void prep_weights(const float* __restrict__ Wq, const float* __restrict__ kv1,
                             const float* __restrict__ kv2, const float* __restrict__ proj,
                             const float* __restrict__ sr1w, const float* __restrict__ sr2w,
                             float* __restrict__ ws, _Float16* __restrict__ Qh,
                             _Float16* __restrict__ Kh1, _Float16* __restrict__ Kh2) {
    int u = blockIdx.x * blockDim.x + threadIdx.x;
    if (u >= 176128) {
        // Kh pad rows (60 per stream): K=0 -> p=1, accounted by l -= 60 in attn
        int e = u - 176128;              // 0..61439 (grid exact)
        int d = e & 31;
        int rest = e >> 5;               // 0..1919
        if (rest < 960) {
            int n = 260 + rest % 60;
            int bh = rest / 60;          // b*2+h2
            Kh1[((size_t)bh * LMP1 + n) * 32 + d] = (_Float16)0.f;
        } else {
            rest -= 960;
            int n = 1028 + rest % 60;
            int bh = rest / 60;
            Kh2[((size_t)bh * LMP2 + n) * 32 + d] = (_Float16)0.f;
        }
        return;
    }
    if (u >= 49152) {
        int idx = u - 49152;             // 0..126975 (exact)
        int d = idx & 31;
        int rest = idx >> 5;
        int n = NTOT + rest % (NPAD - NTOT);
        int rest2 = rest / (NPAD - NTOT);
        int hg = rest2 & 3;
        int b = rest2 >> 2;
        Qh[((size_t)(b * 4 + hg) * NPAD + n) * 32 + d] = (_Float16)0.f;
        return;
    }
    int seg, base;
    const float* w = nullptr;
    _Float16* dst;
    if (u < 2048)        { seg = 0; base = u;          w = Wq;   dst = (_Float16*)(ws + OFF_WFQ); }
    else if (u < 4096)   { seg = 0; base = u - 2048;   w = kv1;  dst = (_Float16*)(ws + OFF_WFKV1); }
    else if (u < 6144)   { seg = 0; base = u - 4096;   w = kv2;  dst = (_Float16*)(ws + OFF_WFKV2); }
    else if (u < 8192)   { seg = 0; base = u - 6144;   w = proj; dst = (_Float16*)(ws + OFF_WFPROJ); }
    else if (u < 40960)  { seg = 1; base = u - 8192;   w = sr1w; dst = (_Float16*)(ws + OFF_WFSR1); }
    else                 { seg = 2; base = u - 40960;  w = sr2w; dst = (_Float16*)(ws + OFF_WFSR2); }
    int lane = base & 63;
    int t = (base >> 6) & 7;
    int kc = base >> 9;
    int n = t * 16 + (lane & 15);
    int k0 = kc * 32 + (lane >> 4) * 8;
    half8v val;
    #pragma unroll
    for (int j = 0; j < 8; ++j) {
        int k = k0 + j;
        float v;
        if (seg == 0) v = w[n * 128 + k];
        else if (seg == 1) v = w[(n * 128 + (k & 127)) * 16 + (k >> 7)];
        else v = w[(n * 128 + (k & 127)) * 4 + (k >> 7)];
        val[j] = (_Float16)v;
    }
    *(half8v*)(dst + (size_t)base * 8) = val;
}

// ---------------- SR partial gemm (fused im2col gather), K-slice per wave ----------------
template<int S, int WR, int LL, int LM, int KW>
__device__ __forceinline__ void sr_partial(
    int mtile, int kcbase, int lane, const float* __restrict__ x,
    const float* __restrict__ msg, const _Float16* __restrict__ Wf, f32x4 acc[8]) {
    int m15 = lane & 15, quadk = lane >> 4;
    int m = mtile * 16 + m15;
    bool valid = m < BB * LM;
    const float* base = x;
    bool isimg = false;
    if (valid) {
        int b = m / LM, tok = m - b * LM;
        if (tok < LL) {
            int hr = tok / WR, wr = tok - hr * WR;
            base = x + ((size_t)b * N0 + hr * S * IMG + wr * S) * 128;
            isimg = true;
        } else {
            base = msg + ((size_t)b * MSGN + (tok - LL)) * 128;
        }
    }
    const half8v* Bp = (const half8v*)Wf + lane;
    for (int kk = 0; kk < KW; ++kk) {
        int kc = kcbase + kk;
        int k0 = (kc * 4 + quadk) * 8;
        int c = k0 & 127, ij = k0 >> 7;
        half8v a;
        if (valid) {
            int off;
            if (isimg) {
                int ki = ij / S, kj = ij - ki * S;
                off = (ki * IMG + kj) * 128 + c;
            } else off = c;
            const float4* p4 = (const float4*)(base + off);
            float4 f0 = p4[0], f1 = p4[1];
            a[0] = (_Float16)f0.x; a[1] = (_Float16)f0.y; a[2] = (_Float16)f0.z; a[3] = (_Float16)f0.w;
            a[4] = (_Float16)f1.x; a[5] = (_Float16)f1.y; a[6] = (_Float16)f1.z; a[7] = (_Float16)f1.w;
        } else {
            #pragma unroll
            for (int j = 0; j < 8; ++j) a[j] = (_Float16)0.f;
        }
        #pragma unroll
        for (int t = 0; t < 8; ++t)
            acc[t] = __builtin_amdgcn_mfma_f32_16x16x32_f16(a, Bp[(size_t)(kc * 8 + t) * 64], acc[t], 0, 0, 0);
    }
}

// ---------------- fused input gemms + KV projection ----------------
// [0,132)    SR1: split-K x4, LDS reduce, LN+GELU, then fused KV gemm (XK stays in LDS)
// [132,261)  SR2: full-K per wave, in-register LN+GELU, per-wave fused KV gemm
// [261,1286) Q projection, N-split x2
// K-halves written directly to Kh (fp16 final layout); V-halves to vo (fp32, 64-wide).
__global__ __launch_bounds__(256) void input_gemms(
    const float* __restrict__ x, const float* __restrict__ msg,
    const _Float16* __restrict__ Wf1, const _Float16* __restrict__ Wf2,
    const float* __restrict__ b1, const float* __restrict__ g1, const float* __restrict__ be1,
    const float* __restrict__ b2, const float* __restrict__ g2, const float* __restrict__ be2,
    const _Float16* __restrict__ WfKV1, const _Float16* __restrict__ WfKV2,
    const float* __restrict__ kvb1, const float* __restrict__ kvb2,
    _Float16* __restrict__ Kh1, float* __restrict__ vo1,
    _Float16* __restrict__ Kh2, float* __restrict__ vo2,
    const _Float16* __restrict__ WfQ, const float* __restrict__ bq,
    _Float16* __restrict__ Qh) {
    __shared__ float red[4][2048];
    int tid = threadIdx.x;
    int lane = tid & 63, wave = tid >> 6;
    int bid = blockIdx.x;
    const f32x4 zf4 = {0.f, 0.f, 0.f, 0.f};

    if (bid >= 261) {
        // ---- q projection path (direct x/msg gather, K=128), N-split x2 ----
        int u = (bid - 261) * 4 + wave;        // 0..4099
        int mt = u >> 1, nh = u & 1;
        int m15 = lane & 15, quadk = lane >> 4;
        int m = mt * 16 + m15;
        bool valid = m < BB * NTOT;
        const float* rowp = x;
        if (valid) {
            int b = m / NTOT, n = m - b * NTOT;
            rowp = (n < N0) ? (x + ((size_t)b * N0 + n) * 128)
                            : (msg + ((size_t)b * MSGN + (n - N0)) * 128);
        }
        const half8v* Bp = (const half8v*)WfQ + lane;
        f32x4 acc[4];
        #pragma unroll
        for (int t = 0; t < 4; ++t) acc[t] = zf4;
        #pragma unroll
        for (int kc = 0; kc < 4; ++kc) {
            half8v a;
            if (valid) {
                const float4* p4 = (const float4*)(rowp + (kc * 4 + quadk) * 8);
                float4 f0 = p4[0], f1 = p4[1];
                a[0] = (_Float16)f0.x; a[1] = (_Float16)f0.y; a[2] = (_Float16)f0.z; a[3] = (_Float16)f0.w;
                a[4] = (_Float16)f1.x; a[5] = (_Float16)f1.y; a[6] = (_Float16)f1.z; a[7] = (_Float16)f1.w;
            } else {
                #pragma unroll
                for (int j = 0; j < 8; ++j) a[j] = (_Float16)0.f;
            }
            #pragma unroll
            for (int t = 0; t < 4; ++t)
                acc[t] = __builtin_amdgcn_mfma_f32_16x16x32_f16(a, Bp[(size_t)(kc * 8 + nh * 4 + t) * 64], acc[t], 0, 0, 0);
        }
        int quad = lane >> 4, n15 = lane & 15;
        // 1/sqrt(32) * log2(e): attn uses exp2 directly on the scores
        const float qscale = 0.17677669529663687f * 1.4426950408889634f;
        #pragma unroll
        for (int r = 0; r < 4; ++r) {
            int mm = mt * 16 + quad * 4 + r;
            if (mm >= BB * NTOT) continue;
            int b = mm / NTOT, tok = mm - b * NTOT;
            #pragma unroll
            for (int t = 0; t < 4; ++t) {
                int n = nh * 64 + t * 16 + n15;
                Qh[((size_t)(b * 4 + (n >> 5)) * NPAD + tok) * 32 + (n & 31)] =
                    (_Float16)((acc[t][r] + bq[n]) * qscale);
            }
        }
        return;
    }

    if (bid >= 132) {
        // ---- SR2: full K=512 per wave, in-register LN+GELU, per-wave fused KV ----
        int mtile = (bid - 132) * 4 + wave;    // 0..515 (514 real)
        f32x4 acc[8];
        #pragma unroll
        for (int t = 0; t < 8; ++t) acc[t] = zf4;
        sr_partial<2, 32, 1024, 1028, 16>(mtile, 0, lane, x, msg, Wf2, acc);
        int quad = lane >> 4, n15 = lane & 15;
        float bb[8], gg[8], eb[8];
        #pragma unroll
        for (int j = 0; j < 8; ++j) {
            bb[j] = b2[j * 16 + n15];
            gg[j] = g2[j * 16 + n15];
            eb[j] = be2[j * 16 + n15];
        }
        // per-wave XK tile in LDS: 16 rows x stride 136 halfs (16B-aligned rows)
        _Float16* XKw = (_Float16*)(&red[0][0]) + wave * 2176;
        #pragma unroll
        for (int r = 0; r < 4; ++r) {
            float s = 0.f;
            #pragma unroll
            for (int j = 0; j < 8; ++j) s += acc[j][r] + bb[j];
            #pragma unroll
            for (int off = 1; off < 16; off <<= 1) s += __shfl_xor(s, off);
            float mu = s * (1.f / 128.f);
            float q = 0.f;
            #pragma unroll
            for (int j = 0; j < 8; ++j) { float d = acc[j][r] + bb[j] - mu; q += d * d; }
            #pragma unroll
            for (int off = 1; off < 16; off <<= 1) q += __shfl_xor(q, off);
            float rs = rsqrtf(q * (1.f / 128.f) + 1e-5f);
            #pragma unroll
            for (int j = 0; j < 8; ++j) {
                float y = (acc[j][r] + bb[j] - mu) * rs * gg[j] + eb[j];
                y = 0.5f * y * (1.f + erff(y * 0.70710678118654752f));
                XKw[(quad * 4 + r) * 136 + j * 16 + n15] = (_Float16)y;
            }
        }
        __syncthreads();       // within-wave RAW fence (all waves uniform path)
        // fused KV: full 16x128 output for this tile
        const half8v* Bp = (const half8v*)WfKV2 + lane;
        f32x4 ka[8];
        #pragma unroll
        for (int tt = 0; tt < 8; ++tt) ka[tt] = zf4;
        #pragma unroll
        for (int kc = 0; kc < 4; ++kc) {
            half8v a = *(const half8v*)&XKw[(lane & 15) * 136 + kc * 32 + (lane >> 4) * 8];
            #pragma unroll
            for (int tt = 0; tt < 8; ++tt)
                ka[tt] = __builtin_amdgcn_mfma_f32_16x16x32_f16(a, Bp[(size_t)(kc * 8 + tt) * 64], ka[tt], 0, 0, 0);
        }
        #pragma unroll
        for (int r = 0; r < 4; ++r) {
            int m = mtile * 16 + quad * 4 + r;
            if (m >= 8224) continue;
            int b = m / 1028, tok = m - b * 1028;
            #pragma unroll
            for (int tt = 0; tt < 8; ++tt) {
                int n = tt * 16 + n15;
                float val = ka[tt][r] + kvb2[n];
                if (tt < 4) {
                    Kh2[((size_t)(b * 2 + (n >> 5)) * LMP2 + tok) * 32 + (n & 31)] = (_Float16)val;
                } else {
                    vo2[((size_t)b * 1028 + tok) * 64 + (n - 64)] = val;
                }
            }
        }
        return;
    }

    // ---- SR1: split-K x4 per m-tile, LDS reduce, LN+GELU, block-fused KV ----
    f32x4 acc[8];
    #pragma unroll
    for (int t = 0; t < 8; ++t) acc[t] = zf4;
    int mtile = bid;
    sr_partial<4, 16, 256, 260, 16>(mtile, wave * 16, lane, x, msg, Wf1, acc);
    int quad = lane >> 4, n15 = lane & 15;
    #pragma unroll
    for (int t = 0; t < 8; ++t)
        #pragma unroll
        for (int r = 0; r < 4; ++r)
            red[wave][(quad * 4 + r) * 128 + t * 16 + n15] = acc[t][r];
    __syncthreads();
    for (int e = tid; e < 2048; e += 256)
        red[0][e] = red[0][e] + red[1][e] + red[2][e] + red[3][e];
    __syncthreads();
    int r16 = tid >> 4, l16 = tid & 15;
    int m = mtile * 16 + r16;
    float v[8];
    float s = 0.f;
    #pragma unroll
    for (int j = 0; j < 8; ++j) { v[j] = red[0][r16 * 128 + j * 16 + l16] + b1[j * 16 + l16]; s += v[j]; }
    #pragma unroll
    for (int off = 1; off < 16; off <<= 1) s += __shfl_xor(s, off);
    float mu = s * (1.f / 128.f);
    float q = 0.f;
    #pragma unroll
    for (int j = 0; j < 8; ++j) { v[j] -= mu; q += v[j] * v[j]; }
    #pragma unroll
    for (int off = 1; off < 16; off <<= 1) q += __shfl_xor(q, off);
    float rs = rsqrtf(q * (1.f / 128.f) + 1e-5f);
    // XK tile to LDS (red[1] area, disjoint from red[0] reads above)
    _Float16* XKs = (_Float16*)(&red[1][0]);     // 16 x stride-136 halfs
    if (m < 2080) {
        #pragma unroll
        for (int j = 0; j < 8; ++j) {
            float y = v[j] * rs * g1[j * 16 + l16] + be1[j * 16 + l16];
            y = 0.5f * y * (1.f + erff(y * 0.70710678118654752f));
            XKs[r16 * 136 + j * 16 + l16] = (_Float16)y;
        }
    }
    __syncthreads();
    // fused KV: wave w covers t = 2w, 2w+1 (waves 0,1 -> K cols; 2,3 -> V cols)
    {
        const half8v* Bp = (const half8v*)WfKV1 + lane;
        int t0 = wave * 2;
        f32x4 ka[2];
        ka[0] = zf4; ka[1] = zf4;
        #pragma unroll
        for (int kc = 0; kc < 4; ++kc) {
            half8v a = *(const half8v*)&XKs[(lane & 15) * 136 + kc * 32 + (lane >> 4) * 8];
            #pragma unroll
            for (int tt = 0; tt < 2; ++tt)
                ka[tt] = __builtin_amdgcn_mfma_f32_16x16x32_f16(a, Bp[(size_t)(kc * 8 + t0 + tt) * 64], ka[tt], 0, 0, 0);
        }
        #pragma unroll
        for (int r = 0; r < 4; ++r) {
            int mm = mtile * 16 + quad * 4 + r;
            if (mm >= 2080) continue;
            int b = mm / 260, tok = mm - b * 260;
            #pragma unroll
            for (int tt = 0; tt < 2; ++tt) {
                int n = (t0 + tt) * 16 + n15;
                float val = ka[tt][r] + kvb1[n];
                if (n < 64) {
                    Kh1[((size_t)(b * 2 + (n >> 5)) * LMP1 + tok) * 32 + (n & 31)] = (_Float16)val;
                } else {
                    vo1[((size_t)b * 260 + tok) * 64 + (n - 64)] = val;
                }
            }
        }
    }
}

// ---------------- V-fixup + fp16 pack (V only; K already in Kh) ----------------
// Vt layout: [b,h2][key>>2][d16:16][dhalf:2][key&3] so a lane's PV B-frag
// (both d-halves) is one contiguous 16B load.
__global__ void pack_kv(const float* __restrict__ vo1, const float* __restrict__ vo2,
                        const float* __restrict__ lc1w, const float* __restrict__ lc1b,
                        const float* __restrict__ lc2w, const float* __restrict__ lc2b,
                        _Float16* __restrict__ Vt1, _Float16* __restrict__ Vt2) {
    int idx = blockIdx.x * 256 + threadIdx.x;
    const int T1 = BB * LMP1 * 64;
    const float* vo;
    const float* lcw;
    const float* lcb;
    _Float16* Vt;
    int Wr, L, Lm, Lmp, li;
    if (idx < T1) { li = idx;      vo = vo1; lcw = lc1w; lcb = lc1b; Vt = Vt1; Wr = 16; L = 256;  Lm = 260;  Lmp = LMP1; }
    else          { li = idx - T1; vo = vo2; lcw = lc2w; lcb = lc2b; Vt = Vt2; Wr = 32; L = 1024; Lm = 1028; Lmp = LMP2; }
    int ch = li & 63;
    int rest = li >> 6;
    int n = rest % Lmp;
    int b = rest / Lmp;
    int h2 = ch >> 5, d = ch & 31;
    int Hr = L / Wr;
    float vnew = 0.f;
    if (n < Lm) {
        const float* vb2 = vo + (size_t)b * Lm * 64;
        float v = vb2[(size_t)n * 64 + ch];
        float add;
        if (n < L) {
            int hr = n / Wr, wr = n - hr * Wr;
            float sum = lcb[ch];
            #pragma unroll
            for (int ki = 0; ki < 3; ++ki)
                #pragma unroll
                for (int kj = 0; kj < 3; ++kj) {
                    int y = hr + ki - 1, xx = wr + kj - 1;
                    if ((unsigned)y < (unsigned)Hr && (unsigned)xx < (unsigned)Wr)
                        sum += lcw[ch * 9 + ki * 3 + kj] * vb2[((size_t)y * Wr + xx) * 64 + ch];
                }
            add = sum;
        } else {
            add = v;   // msg tokens: v_add = v => v_new = 2v
        }
        vnew = v + add;
    }
    Vt[(size_t)(b * 2 + h2) * Lmp * 32 + (size_t)(n >> 2) * 128
       + (d & 15) * 8 + ((d >> 4) << 2) + (n & 3)] = (_Float16)vnew;
}

// ---------------- flash attention: LDS-staged K/V, triple-buffer + counted vmcnt ----------------
// Pipeline (T3/T4): stage tile t+2 async, compute tile t, then s_waitcnt vmcnt(2)
// (waits only for tile t+1's loads, which had a full compute phase to land) + raw
// s_barrier. __syncthreads would drain vmcnt(0) = serialize on the JUST-issued loads.
// Buffer (t+2)%3 was last read in iteration t-1 (fenced by that barrier) -> safe.
// Row-sum l via MFMA with B = ones (same accumulator layout as O).
// Pad keys (60/branch): K=0 -> p=1 -> l -= 60; V=0 so O unaffected.
__global__ __launch_bounds__(256, 4) void attn_mfma(
    const _Float16* __restrict__ Qh,
    const _Float16* __restrict__ Kh1, const _Float16* __restrict__ Vt1,
    const _Float16* __restrict__ Kh2, const _Float16* __restrict__ Vt2,
    _Float16* __restrict__ XP) {
    __shared__ _Float16 sK[3][2048];
    __shared__ _Float16 sV[3][2048];
    int tid = threadIdx.x;
    int lane = tid & 63, wave = tid >> 6;
    int b = blockIdx.y;
    int z = blockIdx.z;
    int h2 = z & 1, br = 1 - (z >> 1);     // long blocks (br=1) dispatch first
    int tile = blockIdx.x * 4 + wave;      // 0..131, all valid (NPAD=4224)
    int n0 = tile * 32;
    int q16 = lane & 15, quad = lane >> 4;
    const f32x4 zf = {0.f, 0.f, 0.f, 0.f};
    int NT = br ? (LMP2 / 64) : (LMP1 / 64);
    int Lmp = br ? LMP2 : LMP1;
    const _Float16* kb = (br ? Kh2 : Kh1) + (size_t)(b * 2 + h2) * Lmp * 32;
    const _Float16* vb = (br ? Vt2 : Vt1) + (size_t)(b * 2 + h2) * Lmp * 32;
    int hg = br * 2 + h2;
    const _Float16* qp = Qh + ((size_t)(b * 4 + hg) * NPAD + n0 + q16) * 32 + quad * 8;
    half8v qf0 = *(const half8v*)qp;
    half8v qf1 = *(const half8v*)(qp + 512);   // +16 rows
    f32x4 O00 = zf, O01 = zf, O10 = zf, O11 = zf;
    f32x4 La = zf, Lb = zf;                    // row-sum accumulators (P @ ones)
    half4v ones4;
    #pragma unroll
    for (int r = 0; r < 4; ++r) ones4[r] = (_Float16)1.f;

    // per-lane staging source offsets within a 64-key tile (2048 halfs).
    int ksrc = (wave * 16 + q16) * 32 + quad * 8;
    int vsrc = wave * 512 + lane * 8;

    // prologue: stage tiles 0 and 1 (NT >= 5 always)
    gload16(kb + ksrc, &sK[0][wave * 512]);
    gload16(vb + vsrc, &sV[0][wave * 512]);
    gload16(kb + 2048 + ksrc, &sK[1][wave * 512]);
    gload16(vb + 2048 + vsrc, &sV[1][wave * 512]);
    asm volatile("s_waitcnt vmcnt(2)" ::: "memory");   // tile 0 landed; tile 1 in flight
    __builtin_amdgcn_sched_barrier(0);
    __builtin_amdgcn_s_barrier();

    for (int t = 0; t < NT; ++t) {
        int cur = t % 3;
        if (t + 2 < NT) {                       // stage tile t+2 (slot last read at t-1)
            int nxt = (t + 2) % 3;
            size_t o = (size_t)(t + 2) * 2048;
            gload16(kb + o + ksrc, &sK[nxt][wave * 512]);
            gload16(vb + o + vsrc, &sV[nxt][wave * 512]);
        }
        half8v kf[4], vv[4];
        #pragma unroll
        for (int i = 0; i < 4; ++i)
            kf[i] = *(const half8v*)&sK[cur][i * 512 + lane * 8];
        #pragma unroll
        for (int i = 0; i < 4; ++i)
            vv[i] = *(const half8v*)&sV[cur][i * 512 + quad * 128 + q16 * 8];

        __builtin_amdgcn_s_setprio(1);
        // S = K·Q^T for both q-tiles, exp2 -> p (scores already log2-scaled)
        half4v p0[4], p1[4];
        #pragma unroll
        for (int i = 0; i < 4; ++i) {
            f32x4 s0 = __builtin_amdgcn_mfma_f32_16x16x32_f16(kf[i], qf0, zf, 0, 0, 0);
            f32x4 s1 = __builtin_amdgcn_mfma_f32_16x16x32_f16(kf[i], qf1, zf, 0, 0, 0);
            half4v a, c;
            #pragma unroll
            for (int r = 0; r < 4; ++r) {
                a[r] = (_Float16)exp2_fast(s0[r]);
                c[r] = (_Float16)exp2_fast(s1[r]);
            }
            p0[i] = a; p1[i] = c;
        }
        // PV + row-sum for both q-tiles
        #pragma unroll
        for (int i = 0; i < 4; ++i) {
            half4v v0 = __builtin_shufflevector(vv[i], vv[i], 0, 1, 2, 3);
            half4v v1 = __builtin_shufflevector(vv[i], vv[i], 4, 5, 6, 7);
            O00 = __builtin_amdgcn_mfma_f32_16x16x16f16(p0[i], v0, O00, 0, 0, 0);
            O01 = __builtin_amdgcn_mfma_f32_16x16x16f16(p0[i], v1, O01, 0, 0, 0);
            La  = __builtin_amdgcn_mfma_f32_16x16x16f16(p0[i], ones4, La, 0, 0, 0);
            O10 = __builtin_amdgcn_mfma_f32_16x16x16f16(p1[i], v0, O10, 0, 0, 0);
            O11 = __builtin_amdgcn_mfma_f32_16x16x16f16(p1[i], v1, O11, 0, 0, 0);
            Lb  = __builtin_amdgcn_mfma_f32_16x16x16f16(p1[i], ones4, Lb, 0, 0, 0);
        }
        __builtin_amdgcn_s_setprio(0);

        // guard: tile t+1's loads retired (only t+2's 2 loads may stay in flight)
        if (t + 2 < NT) asm volatile("s_waitcnt vmcnt(2)" ::: "memory");
        else            asm volatile("s_waitcnt vmcnt(0)" ::: "memory");
        __builtin_amdgcn_sched_barrier(0);
        __builtin_amdgcn_s_barrier();
    }

    // normalize + store: row = quad*4+r; l for that row is La[r]/Lb[r] (all cols equal)
    int kbase = br * 64 + h2 * 32;
    #pragma unroll
    for (int r = 0; r < 4; ++r) {
        float fa = 1.0f / (La[r] - 60.0f);     // 60 pad keys contribute p=1
        float fb = 1.0f / (Lb[r] - 60.0f);
        int n = n0 + quad * 4 + r;
        if (n < NTOT) {
            int m = b * NTOT + n;
            XP[af_idx(m, kbase + q16, 4)] = (_Float16)(O00[r] * fa);
            XP[af_idx(m, kbase + 16 + q16, 4)] = (_Float16)(O01[r] * fa);
        }
        int n2 = n + 16;
        if (n2 < NTOT) {
            int m = b * NTOT + n2;
            XP[af_idx(m, kbase + q16, 4)] = (_Float16)(O10[r] * fb);
            XP[af_idx(m, kbase + 16 + q16, 4)] = (_Float16)(O11[r] * fb);
        }
    }
}

// ---------------- final projection: XP (normalized fp16) + residual, N-split x2 ----------------
__global__ __launch_bounds__(256) void proj_gemm(
    const _Float16* __restrict__ XP,
    const _Float16* __restrict__ Wf, const float* __restrict__ bias,
    float* __restrict__ out_f32, const float* __restrict__ x, const float* __restrict__ msg) {
    int lane = threadIdx.x & 63, wave = threadIdx.x >> 6;
    int u = blockIdx.x * 4 + wave;      // 0..4099
    int mt = u >> 1, nh = u & 1;
    const half8v* Ap = (const half8v*)XP + (size_t)mt * 4 * 64 + lane;
    const half8v* Bp = (const half8v*)Wf + lane;
    f32x4 acc[4];
    #pragma unroll
    for (int t = 0; t < 4; ++t) acc[t] = (f32x4){0.f, 0.f, 0.f, 0.f};
    #pragma unroll
    for (int kc = 0; kc < 4; ++kc) {
        half8v a = Ap[(size_t)kc * 64];
        #pragma unroll
        for (int t = 0; t < 4; ++t)
            acc[t] = __builtin_amdgcn_mfma_f32_16x16x32_f16(a, Bp[(size_t)(kc * 8 + nh * 4 + t) * 64], acc[t], 0, 0, 0);
    }
    int quad = lane >> 4, n15 = lane & 15;
    #pragma unroll
    for (int r = 0; r < 4; ++r) {
        int m = mt * 16 + quad * 4 + r;
        if (m >= BB * NTOT) continue;
        int b = m / NTOT, tok = m - b * NTOT;
        const float* rp;
        float* dst;
        if (tok < N0) {
            rp = x + ((size_t)b * N0 + tok) * 128;
            dst = out_f32 + ((size_t)b * N0 + tok) * 128;
        } else {
            rp = msg + ((size_t)b * MSGN + (tok - N0)) * 128;
            dst = out_f32 + (size_t)BB * N0 * 128 + ((size_t)b * MSGN + (tok - N0)) * 128;
        }
        #pragma unroll
        for (int t = 0; t < 4; ++t) {
            int n = nh * 64 + t * 16 + n15;
            dst[n] = acc[t][r] + bias[n] + rp[n];
        }
    }
}

extern "C" void kernel_launch(void* const* d_in, const int* in_sizes, int n_in,
                              void* d_out, int out_size, void* d_ws, size_t ws_size,
                              hipStream_t stream) {
    const float* x     = (const float*)d_in[0];
    const float* msg   = (const float*)d_in[1];
    const float* Wq    = (const float*)d_in[2];
    const float* bq    = (const float*)d_in[3];
    const float* sr1w  = (const float*)d_in[4];
    const float* sr1b  = (const float*)d_in[5];
    const float* ln1g  = (const float*)d_in[6];
    const float* ln1b  = (const float*)d_in[7];
    const float* sr2w  = (const float*)d_in[8];
    const float* sr2b  = (const float*)d_in[9];
    const float* ln2g  = (const float*)d_in[10];
    const float* ln2b  = (const float*)d_in[11];
    const float* kv1w  = (const float*)d_in[12];
    const float* kv1b  = (const float*)d_in[13];
    const float* kv2w  = (const float*)d_in[14];
    const float* kv2b  = (const float*)d_in[15];
    const float* lc1w  = (const float*)d_in[16];
    const float* lc1b  = (const float*)d_in[17];
    const float* lc2w  = (const float*)d_in[18];
    const float* lc2b  = (const float*)d_in[19];
    const float* projw = (const float*)d_in[20];
    const float* projb = (const float*)d_in[21];
    float* ws  = (float*)d_ws;
    float* out = (float*)d_out;

    _Float16* WfQ    = (_Float16*)(ws + OFF_WFQ);
    _Float16* WfKV1  = (_Float16*)(ws + OFF_WFKV1);
    _Float16* WfKV2  = (_Float16*)(ws + OFF_WFKV2);
    _Float16* WfPROJ = (_Float16*)(ws + OFF_WFPROJ);
    _Float16* WfSR1  = (_Float16*)(ws + OFF_WFSR1);
    _Float16* WfSR2  = (_Float16*)(ws + OFF_WFSR2);
    _Float16* Qh     = (_Float16*)(ws + OFF_QH);
    _Float16* XP     = (_Float16*)(ws + OFF_XP);
    float* vo1       = ws + OFF_KV1O;
    float* vo2       = ws + OFF_KV2O;
    _Float16* Kh1    = (_Float16*)(ws + OFF_KH1);
    _Float16* Vt1    = (_Float16*)(ws + OFF_VT1);
    _Float16* Kh2    = (_Float16*)(ws + OFF_KH2);
    _Float16* Vt2    = (_Float16*)(ws + OFF_VT2);

    // 1. weights swizzle + Q pad zero + Kh pad zero (49152 + 126976 + 61440 threads)
    prep_weights<<<928, 256, 0, stream>>>(Wq, kv1w, kv2w, projw, sr1w, sr2w, ws, Qh, Kh1, Kh2);
    // 2. fused SR convs + LN/GELU + KV projection + q projection
    input_gemms<<<1286, 256, 0, stream>>>(x, msg, WfSR1, WfSR2,
                                          sr1b, ln1g, ln1b, sr2b, ln2g, ln2b,
                                          WfKV1, WfKV2, kv1b, kv2b,
                                          Kh1, vo1, Kh2, vo2,
                                          WfQ, bq, Qh);
    // 3. V fixup + pack (K already final in Kh)
    pack_kv<<<2816, 256, 0, stream>>>(vo1, vo2, lc1w, lc1b, lc2w, lc2b, Vt1, Vt2);
    // 4. flash attention: triple-buffered K/V pipeline, MFMA row-sums
    attn_mfma<<<dim3(33, 8, 4), 256, 0, stream>>>(Qh, Kh1, Vt1, Kh2, Vt2, XP);
    // 5. final projection + residual, N-split x2
    proj_gemm<<<1025, 256, 0, stream>>>(XP, WfPROJ, projb, out, x, msg);
}